// Round 2
// baseline (766.212 us; speedup 1.0000x reference)
//
#include <hip/hip_runtime.h>

// Attention_6219112645023 — fp32 in / fp32 out, bf16 internal compute (MFMA).
// B=2, T=2048, DIM=2048, NH=32, NKV=8, HD=64. Causal GQA + RoPE + projections.
// Pipeline: gemm(Q,+RoPE) gemm(K,+RoPE) gemm(V) transpose(V) flash_attn gemm(O).
// Workspace usage: 44 MB (Qb 16 | Kb 4 | Vb 4 | Vtb 4 | AOb 16), all bf16.

typedef unsigned short u16;
typedef __attribute__((ext_vector_type(8))) short bf16x8;  // 8 bf16 in 4 VGPRs
typedef __attribute__((ext_vector_type(4))) float f32x4;

constexpr int T_SEQ = 2048;
constexpr int DIMC  = 2048;
constexpr int NHEAD = 32;
constexpr int HDIM  = 64;
constexpr int KVDIM = 512;   // NKV * HDIM
constexpr int BATCH = 2;

__device__ __forceinline__ u16 f2bf(float f) {
    union { float f; unsigned int i; } v; v.f = f;
    unsigned int r = v.i + 0x7FFFu + ((v.i >> 16) & 1u);   // RNE
    return (u16)(r >> 16);
}

// ---------------------------------------------------------------------------
// C[M][N] = A[M][K] · W[N][K]^T   (bf16 MFMA, fp32 accum)
// A: fp32 (AF32) or bf16. W: always fp32 (model weights). C: fp32 or bf16.
// 128x128 tile, BK=32, 256 threads = 4 waves (2x2), each wave 4x4 mfma tiles.
// ROPE: fuse rotary embedding into epilogue (wave's 64-col span == one head).
// ---------------------------------------------------------------------------
template <bool ROPE, bool AF32, bool OUTF32>
__global__ __launch_bounds__(256) void gemm_bt(const void* __restrict__ Av,
                                               const float* __restrict__ W,
                                               void* __restrict__ Cv,
                                               int M, int N, int K) {
    __shared__ __align__(16) u16 As[128][40];   // +8 pad: stride 80B, 16B-aligned
    __shared__ __align__(16) u16 Bs[128][40];

    const int tid  = threadIdx.x;
    const int lane = tid & 63;
    const int w    = tid >> 6;
    const int quad = lane >> 4;
    const int ln   = lane & 15;
    const int rowBase = blockIdx.y * 128;
    const int colBase = blockIdx.x * 128;
    const int wm = (w >> 1) * 64;
    const int wn = (w & 1) * 64;

    f32x4 acc[4][4] = {};

    const int r0 = tid >> 2;          // staging: 128 rows x 32 cols, 8 elems/thread x2
    const int c0 = (tid & 3) * 8;

    for (int kk = 0; kk < K; kk += 32) {
        __syncthreads();
        #pragma unroll
        for (int it = 0; it < 2; ++it) {
            int row = r0 + it * 64;
            // A tile
            bf16x8 va;
            if constexpr (AF32) {
                const float* p = (const float*)Av + (size_t)(rowBase + row) * K + kk + c0;
                f32x4 a0 = *(const f32x4*)p;
                f32x4 a1 = *(const f32x4*)(p + 4);
                #pragma unroll
                for (int e = 0; e < 4; ++e) {
                    va[e]     = (short)f2bf(a0[e]);
                    va[4 + e] = (short)f2bf(a1[e]);
                }
            } else {
                va = *(const bf16x8*)((const u16*)Av + (size_t)(rowBase + row) * K + kk + c0);
            }
            // W tile (fp32 -> bf16)
            const float* q = W + (size_t)(colBase + row) * K + kk + c0;
            f32x4 b0 = *(const f32x4*)q;
            f32x4 b1 = *(const f32x4*)(q + 4);
            bf16x8 vb;
            #pragma unroll
            for (int e = 0; e < 4; ++e) {
                vb[e]     = (short)f2bf(b0[e]);
                vb[4 + e] = (short)f2bf(b1[e]);
            }
            *(bf16x8*)&As[row][c0] = va;
            *(bf16x8*)&Bs[row][c0] = vb;
        }
        __syncthreads();

        bf16x8 af[4], bw[4];
        #pragma unroll
        for (int i = 0; i < 4; ++i) af[i] = *(const bf16x8*)&As[wm + i * 16 + ln][quad * 8];
        #pragma unroll
        for (int j = 0; j < 4; ++j) bw[j] = *(const bf16x8*)&Bs[wn + j * 16 + ln][quad * 8];
        #pragma unroll
        for (int i = 0; i < 4; ++i)
            #pragma unroll
            for (int j = 0; j < 4; ++j)
                acc[i][j] = __builtin_amdgcn_mfma_f32_16x16x32_bf16(af[i], bw[j], acc[i][j], 0, 0, 0);
    }

    if (ROPE) {
        // col n = colBase + wn + j*16 + ln; head-local d = n % 64 = j*16+ln.
        // pairs: (d, d+32) -> (acc[i][j], acc[i][j+2]) for j in {0,1}.
        // out[d] = a[d]*cos - a[d+32]*sin ; out[d+32] = a[d+32]*cos + a[d]*sin
        #pragma unroll
        for (int i = 0; i < 4; ++i) {
            #pragma unroll
            for (int j = 0; j < 2; ++j) {
                int d = j * 16 + ln;                       // 0..31
                float invf = exp2f(-(float)d * (13.287712379549449f / 32.0f));
                #pragma unroll
                for (int r = 0; r < 4; ++r) {
                    int mrow = rowBase + wm + i * 16 + quad * 4 + r;
                    int t = mrow & (T_SEQ - 1);            // token position in sequence
                    float fr = (float)t * invf;
                    float sn, cs;
                    sincosf(fr, &sn, &cs);
                    float a0 = acc[i][j][r], a2 = acc[i][j + 2][r];
                    acc[i][j][r]     = a0 * cs - a2 * sn;
                    acc[i][j + 2][r] = a2 * cs + a0 * sn;
                }
            }
        }
    }

    #pragma unroll
    for (int i = 0; i < 4; ++i) {
        int mrow = rowBase + wm + i * 16 + quad * 4;
        #pragma unroll
        for (int j = 0; j < 4; ++j) {
            int n = colBase + wn + j * 16 + ln;
            #pragma unroll
            for (int r = 0; r < 4; ++r) {
                if constexpr (OUTF32)
                    ((float*)Cv)[(size_t)(mrow + r) * N + n] = acc[i][j][r];
                else
                    ((u16*)Cv)[(size_t)(mrow + r) * N + n] = f2bf(acc[i][j][r]);
            }
        }
    }
}

// ---------------------------------------------------------------------------
// V [B*T][KVDIM] -> Vt [B][KVDIM][T]  (32x32 LDS tile transpose, bf16)
// ---------------------------------------------------------------------------
__global__ __launch_bounds__(256) void transpose_v(const u16* __restrict__ V,
                                                   u16* __restrict__ Vt) {
    __shared__ __align__(16) u16 tile[32][33];
    const int x = threadIdx.x & 31;
    const int y = threadIdx.x >> 5;              // 0..7
    const int tok0 = blockIdx.y * 32;            // never straddles batch boundary
    const int c0   = blockIdx.x * 32;
    #pragma unroll
    for (int yy = 0; yy < 32; yy += 8)
        tile[y + yy][x] = V[(size_t)(tok0 + y + yy) * KVDIM + c0 + x];
    __syncthreads();
    const int b  = tok0 >> 11;
    const int t0 = tok0 & (T_SEQ - 1);
    #pragma unroll
    for (int yy = 0; yy < 32; yy += 8)
        Vt[(size_t)(b * KVDIM + c0 + y + yy) * T_SEQ + t0 + x] = tile[x][y + yy];
}

// ---------------------------------------------------------------------------
// Flash attention. grid = (T/64, NH, B), block = 256 (4 waves x 16 queries).
// Q frags in registers for the whole K-loop; K and V^T staged per 32-key tile.
// S = mfma(Q, K^T) -> causal mask + online softmax -> P via per-wave LDS
// (C-layout -> A-layout) -> O += mfma(P, V).  All buffers bf16.
// ---------------------------------------------------------------------------
__global__ __launch_bounds__(256) void attn(const u16* __restrict__ Q,
                                            const u16* __restrict__ Kx,
                                            const u16* __restrict__ Vt,
                                            u16* __restrict__ O) {
    __shared__ __align__(16) u16 Ks[32][72];       // [key][dim]  stride 144B
    __shared__ __align__(16) u16 Vs[64][40];       // [dim][key]  stride 80B
    __shared__ __align__(16) u16 Ps[4][16][40];    // per-wave P [q][key], stride 80B

    const int tid  = threadIdx.x;
    const int lane = tid & 63;
    const int w    = tid >> 6;
    const int quad = lane >> 4;
    const int ln   = lane & 15;
    const int qblk = blockIdx.x;
    const int h    = blockIdx.y;
    const int b    = blockIdx.z;
    const int kvh  = h >> 2;
    const int qr0  = qblk * 64 + w * 16;

    // Q A-fragments: Q[qr0+ln][quad*8+j (+32)]
    const u16* qptr = Q + (size_t)(b * T_SEQ + qr0 + ln) * DIMC + h * HDIM + quad * 8;
    const bf16x8 aq0 = *(const bf16x8*)qptr;
    const bf16x8 aq1 = *(const bf16x8*)(qptr + 32);

    f32x4 o[4] = {};
    float mrun[4], lrun[4];
    #pragma unroll
    for (int r = 0; r < 4; ++r) { mrun[r] = -3.0e38f; lrun[r] = 0.0f; }

    const int kkey = tid >> 3, kdc = (tid & 7) * 8;   // K staging map
    const int vdim = tid >> 2, vkc = (tid & 3) * 8;   // V staging map
    const u16* kbase = Kx + (size_t)(b * T_SEQ) * KVDIM + kvh * HDIM;
    const u16* vbase = Vt + (size_t)(b * KVDIM + kvh * HDIM + vdim) * T_SEQ;

    const int ktmax = (qblk * 64 + 63) >> 5;   // uniform across block
    const float scale = 0.125f;                // 1/sqrt(64)

    for (int kt = 0; kt <= ktmax; ++kt) {
        const int k0 = kt * 32;
        __syncthreads();
        *(bf16x8*)&Ks[kkey][kdc] = *(const bf16x8*)(kbase + (size_t)(k0 + kkey) * KVDIM + kdc);
        *(bf16x8*)&Vs[vdim][vkc] = *(const bf16x8*)(vbase + k0 + vkc);
        __syncthreads();

        // S tiles: two 16-key subtiles, K-dim 64 = 2 mfma chunks each
        bf16x8 bk00 = *(const bf16x8*)&Ks[ln][quad * 8];
        bf16x8 bk01 = *(const bf16x8*)&Ks[ln][32 + quad * 8];
        bf16x8 bk10 = *(const bf16x8*)&Ks[16 + ln][quad * 8];
        bf16x8 bk11 = *(const bf16x8*)&Ks[16 + ln][32 + quad * 8];
        f32x4 s0 = {}, s1 = {};
        s0 = __builtin_amdgcn_mfma_f32_16x16x32_bf16(aq0, bk00, s0, 0, 0, 0);
        s0 = __builtin_amdgcn_mfma_f32_16x16x32_bf16(aq1, bk01, s0, 0, 0, 0);
        s1 = __builtin_amdgcn_mfma_f32_16x16x32_bf16(aq0, bk10, s1, 0, 0, 0);
        s1 = __builtin_amdgcn_mfma_f32_16x16x32_bf16(aq1, bk11, s1, 0, 0, 0);

        // causal mask + online softmax (per query row = quad*4+r)
        #pragma unroll
        for (int r = 0; r < 4; ++r) {
            int qg = qr0 + quad * 4 + r;
            float v0 = (k0 + ln      <= qg) ? s0[r] * scale : -3.0e38f;
            float v1 = (k0 + 16 + ln <= qg) ? s1[r] * scale : -3.0e38f;
            float mt = fmaxf(v0, v1);
            mt = fmaxf(mt, __shfl_xor(mt, 1));
            mt = fmaxf(mt, __shfl_xor(mt, 2));
            mt = fmaxf(mt, __shfl_xor(mt, 4));
            mt = fmaxf(mt, __shfl_xor(mt, 8));
            float mnew  = fmaxf(mrun[r], mt);          // finite: key 0 always unmasked
            float alpha = __expf(mrun[r] - mnew);
            float e0 = __expf(v0 - mnew);
            float e1 = __expf(v1 - mnew);
            float rs = e0 + e1;
            rs += __shfl_xor(rs, 1);
            rs += __shfl_xor(rs, 2);
            rs += __shfl_xor(rs, 4);
            rs += __shfl_xor(rs, 8);
            lrun[r] = lrun[r] * alpha + rs;
            mrun[r] = mnew;
            #pragma unroll
            for (int t = 0; t < 4; ++t) o[t][r] *= alpha;
            Ps[w][quad * 4 + r][ln]      = f2bf(e0);
            Ps[w][quad * 4 + r][16 + ln] = f2bf(e1);
        }
        __syncthreads();   // LDS visibility for the P exchange + Vs reuse

        // P A-frag (K=32 keys) and V B-frags; O += P·V
        bf16x8 pa = *(const bf16x8*)&Ps[w][ln][quad * 8];
        #pragma unroll
        for (int t = 0; t < 4; ++t) {
            bf16x8 bv = *(const bf16x8*)&Vs[t * 16 + ln][quad * 8];
            o[t] = __builtin_amdgcn_mfma_f32_16x16x32_bf16(pa, bv, o[t], 0, 0, 0);
        }
    }

    // epilogue: normalize and store (bf16 intermediate)
    size_t obase = (size_t)(b * T_SEQ + qr0 + quad * 4) * DIMC + h * HDIM;
    #pragma unroll
    for (int r = 0; r < 4; ++r) {
        float inv = 1.0f / lrun[r];
        #pragma unroll
        for (int t = 0; t < 4; ++t)
            O[obase + (size_t)r * DIMC + t * 16 + ln] = f2bf(o[t][r] * inv);
    }
}

// ---------------------------------------------------------------------------
extern "C" void kernel_launch(void* const* d_in, const int* in_sizes, int n_in,
                              void* d_out, int out_size, void* d_ws, size_t ws_size,
                              hipStream_t stream) {
    const float* x  = (const float*)d_in[0];
    const float* wq = (const float*)d_in[1];
    const float* wk = (const float*)d_in[2];
    const float* wv = (const float*)d_in[3];
    const float* wo = (const float*)d_in[4];
    float* out = (float*)d_out;

    char* ws = (char*)d_ws;
    u16* Qb  = (u16*)(ws);                               // 16 MB  [4096][2048]
    u16* Kb  = (u16*)(ws + 16u * 1024 * 1024);           //  4 MB  [4096][512]
    u16* Vb  = (u16*)(ws + 20u * 1024 * 1024);           //  4 MB  [4096][512]
    u16* Vtb = (u16*)(ws + 24u * 1024 * 1024);           //  4 MB  [2][512][2048]
    u16* AOb = (u16*)(ws + 28u * 1024 * 1024);           // 16 MB  [4096][2048]

    const int M = BATCH * T_SEQ;   // 4096

    hipLaunchKernelGGL((gemm_bt<true, true, false>),  dim3(DIMC / 128, M / 128),  dim3(256), 0, stream,
                       x, wq, Qb, M, DIMC, DIMC);
    hipLaunchKernelGGL((gemm_bt<true, true, false>),  dim3(KVDIM / 128, M / 128), dim3(256), 0, stream,
                       x, wk, Kb, M, KVDIM, DIMC);
    hipLaunchKernelGGL((gemm_bt<false, true, false>), dim3(KVDIM / 128, M / 128), dim3(256), 0, stream,
                       x, wv, Vb, M, KVDIM, DIMC);
    hipLaunchKernelGGL(transpose_v, dim3(KVDIM / 32, M / 32), dim3(256), 0, stream, Vb, Vtb);
    hipLaunchKernelGGL(attn, dim3(T_SEQ / 64, NHEAD, BATCH), dim3(256), 0, stream,
                       Qb, Kb, Vtb, AOb);
    hipLaunchKernelGGL((gemm_bt<false, false, true>), dim3(DIMC / 128, M / 128), dim3(256), 0, stream,
                       AOb, wo, out, M, DIMC, DIMC);
}

// Round 3
// 586.389 us; speedup vs baseline: 1.3067x; 1.3067x over previous
//
#include <hip/hip_runtime.h>

// Attention_6219112645023 — fp32 in / fp32 out, bf16 internal compute (MFMA).
// B=2, T=2048, DIM=2048, NH=32, NKV=8, HD=64. Causal GQA + RoPE + projections.
// Fast path (ws >= 64MB): cvt->bf16, fused QKV gemm (global_load_lds), transpose,
// flash attn (128q/64k tiles), O gemm (global_load_lds).
// Fallback (ws >= 44MB): round-2 verified fp32-staging gemms + new attn.

typedef unsigned short u16;
typedef __attribute__((ext_vector_type(8))) short bf16x8;  // 8 bf16 in 4 VGPRs
typedef __attribute__((ext_vector_type(4))) float f32x4;
typedef __attribute__((ext_vector_type(4))) unsigned short u16x4;

constexpr int T_SEQ = 2048;
constexpr int DIMC  = 2048;
constexpr int NHEAD = 32;
constexpr int HDIM  = 64;
constexpr int KVDIM = 512;   // NKV * HDIM
constexpr int BATCH = 2;

__device__ __forceinline__ u16 f2bf(float f) {
    union { float f; unsigned int i; } v; v.f = f;
    unsigned int r = v.i + 0x7FFFu + ((v.i >> 16) & 1u);   // RNE
    return (u16)(r >> 16);
}

typedef __attribute__((address_space(1))) unsigned int as1_uint;
typedef __attribute__((address_space(3))) unsigned int as3_uint;
__device__ __forceinline__ void glds16(const u16* g, u16* l) {
    // async global->LDS, 16B/lane; LDS dest = wave-uniform base + lane*16
    __builtin_amdgcn_global_load_lds((as1_uint*)(u16*)g, (as3_uint*)l, 16, 0, 0);
}

// ===========================================================================
// fp32 -> bf16 elementwise convert (n multiple of 4)
// ===========================================================================
__global__ __launch_bounds__(256) void cvt_bf16(const float* __restrict__ s,
                                                u16* __restrict__ d, int n) {
    for (int i = (blockIdx.x * 256 + threadIdx.x) * 4; i < n; i += gridDim.x * 1024) {
        f32x4 v = *(const f32x4*)(s + i);
        u16x4 o;
        #pragma unroll
        for (int e = 0; e < 4; ++e) o[e] = f2bf(v[e]);
        *(u16x4*)(d + i) = o;
    }
}

// ===========================================================================
// m97-style GEMM core: C = A[M][K] . W[N][K]^T, bf16 in, global_load_lds
// staging into unpadded LDS, 128x128 tile, BK=32, 4 waves x 4x4 mfma tiles.
// rope (runtime, block-uniform): fused rotary on 64-col head spans.
// ===========================================================================
template <bool OUTF32>
__device__ __forceinline__ void gemm_core(const u16* __restrict__ A,
                                          const u16* __restrict__ W,
                                          void* __restrict__ Cv,
                                          int rowBase, int colBase,
                                          int N, int K, bool rope) {
    __shared__ __align__(16) u16 As[128 * 32];   // unpadded: glds lane order
    __shared__ __align__(16) u16 Bs[128 * 32];

    const int tid  = threadIdx.x;
    const int lane = tid & 63;
    const int w    = tid >> 6;
    const int quad = lane >> 4;
    const int ln   = lane & 15;
    const int wm = (w >> 1) * 64;
    const int wn = (w & 1) * 64;

    f32x4 acc[4][4] = {};

    // staging: chunk c = 16 rows; lane i -> row c*16 + (i>>2), col (i&3)*8
    const int srow = lane >> 2;
    const int scol = (lane & 3) * 8;
    const u16* aC0 = A + (size_t)(rowBase + w * 16 + srow) * K + scol;
    const u16* aC1 = A + (size_t)(rowBase + (w + 4) * 16 + srow) * K + scol;
    const u16* bC0 = W + (size_t)(colBase + w * 16 + srow) * K + scol;
    const u16* bC1 = W + (size_t)(colBase + (w + 4) * 16 + srow) * K + scol;
    u16* asl0 = As + w * 512;         // chunk w      (512 elems = 1KB)
    u16* asl1 = As + (w + 4) * 512;
    u16* bsl0 = Bs + w * 512;
    u16* bsl1 = Bs + (w + 4) * 512;

    for (int kk = 0; kk < K; kk += 32) {
        __syncthreads();
        glds16(aC0 + kk, asl0);
        glds16(aC1 + kk, asl1);
        glds16(bC0 + kk, bsl0);
        glds16(bC1 + kk, bsl1);
        __syncthreads();   // vmcnt(0) drain -> staged data visible

        bf16x8 af[4], bw[4];
        #pragma unroll
        for (int i = 0; i < 4; ++i) af[i] = *(const bf16x8*)(As + (wm + i * 16 + ln) * 32 + quad * 8);
        #pragma unroll
        for (int j = 0; j < 4; ++j) bw[j] = *(const bf16x8*)(Bs + (wn + j * 16 + ln) * 32 + quad * 8);
        #pragma unroll
        for (int i = 0; i < 4; ++i)
            #pragma unroll
            for (int j = 0; j < 4; ++j)
                acc[i][j] = __builtin_amdgcn_mfma_f32_16x16x32_bf16(af[i], bw[j], acc[i][j], 0, 0, 0);
    }

    if (rope) {
        // head-local d = (colBase+wn+j*16+ln) % 64 = j*16+ln (colBase%128==0, wn%64==0)
        #pragma unroll
        for (int i = 0; i < 4; ++i) {
            #pragma unroll
            for (int j = 0; j < 2; ++j) {
                int d = j * 16 + ln;
                float invf = exp2f(-(float)d * (13.287712379549449f / 32.0f));
                #pragma unroll
                for (int r = 0; r < 4; ++r) {
                    int mrow = rowBase + wm + i * 16 + quad * 4 + r;
                    int t = mrow & (T_SEQ - 1);
                    float fr = (float)t * invf;
                    float sn, cs;
                    sincosf(fr, &sn, &cs);
                    float a0 = acc[i][j][r], a2 = acc[i][j + 2][r];
                    acc[i][j][r]     = a0 * cs - a2 * sn;
                    acc[i][j + 2][r] = a2 * cs + a0 * sn;
                }
            }
        }
    }

    #pragma unroll
    for (int i = 0; i < 4; ++i) {
        int mrow = rowBase + wm + i * 16 + quad * 4;
        #pragma unroll
        for (int j = 0; j < 4; ++j) {
            int n = colBase + wn + j * 16 + ln;
            #pragma unroll
            for (int r = 0; r < 4; ++r) {
                if constexpr (OUTF32)
                    ((float*)Cv)[(size_t)(mrow + r) * N + n] = acc[i][j][r];
                else
                    ((u16*)Cv)[(size_t)(mrow + r) * N + n] = f2bf(acc[i][j][r]);
            }
        }
    }
}

// Fused QKV: grid.x 0..23 -> Q cols (16 blks) | K cols (4) | V cols (4)
__global__ __launch_bounds__(256) void qkv_gemm(const u16* __restrict__ xb,
                                                const u16* __restrict__ wqb,
                                                const u16* __restrict__ wkb,
                                                const u16* __restrict__ wvb,
                                                u16* __restrict__ Qb,
                                                u16* __restrict__ Kb,
                                                u16* __restrict__ Vb) {
    const int nb = blockIdx.x;
    const int rowBase = blockIdx.y * 128;
    const u16* W; u16* C; int colBase, N; bool rope;
    if (nb < 16)      { W = wqb; C = Qb; colBase = nb * 128;        N = DIMC;  rope = true; }
    else if (nb < 20) { W = wkb; C = Kb; colBase = (nb - 16) * 128; N = KVDIM; rope = true; }
    else              { W = wvb; C = Vb; colBase = (nb - 20) * 128; N = KVDIM; rope = false; }
    gemm_core<false>(xb, W, C, rowBase, colBase, N, DIMC, rope);
}

__global__ __launch_bounds__(256) void gemm_f32out(const u16* __restrict__ A,
                                                   const u16* __restrict__ W,
                                                   float* __restrict__ C,
                                                   int N, int K) {
    gemm_core<true>(A, W, C, blockIdx.y * 128, blockIdx.x * 128, N, K, false);
}

// ===========================================================================
// Round-2 verified fallback GEMM (fp32 A/W staging with convert) — kept for
// the ws_size < 64MB case.
// ===========================================================================
template <bool ROPE, bool AF32, bool OUTF32>
__global__ __launch_bounds__(256) void gemm_bt(const void* __restrict__ Av,
                                               const float* __restrict__ W,
                                               void* __restrict__ Cv,
                                               int M, int N, int K) {
    __shared__ __align__(16) u16 As[128][40];
    __shared__ __align__(16) u16 Bs[128][40];

    const int tid  = threadIdx.x;
    const int lane = tid & 63;
    const int w    = tid >> 6;
    const int quad = lane >> 4;
    const int ln   = lane & 15;
    const int rowBase = blockIdx.y * 128;
    const int colBase = blockIdx.x * 128;
    const int wm = (w >> 1) * 64;
    const int wn = (w & 1) * 64;

    f32x4 acc[4][4] = {};
    const int r0 = tid >> 2;
    const int c0 = (tid & 3) * 8;

    for (int kk = 0; kk < K; kk += 32) {
        __syncthreads();
        #pragma unroll
        for (int it = 0; it < 2; ++it) {
            int row = r0 + it * 64;
            bf16x8 va;
            if constexpr (AF32) {
                const float* p = (const float*)Av + (size_t)(rowBase + row) * K + kk + c0;
                f32x4 a0 = *(const f32x4*)p;
                f32x4 a1 = *(const f32x4*)(p + 4);
                #pragma unroll
                for (int e = 0; e < 4; ++e) { va[e] = (short)f2bf(a0[e]); va[4 + e] = (short)f2bf(a1[e]); }
            } else {
                va = *(const bf16x8*)((const u16*)Av + (size_t)(rowBase + row) * K + kk + c0);
            }
            const float* q = W + (size_t)(colBase + row) * K + kk + c0;
            f32x4 b0 = *(const f32x4*)q;
            f32x4 b1 = *(const f32x4*)(q + 4);
            bf16x8 vb;
            #pragma unroll
            for (int e = 0; e < 4; ++e) { vb[e] = (short)f2bf(b0[e]); vb[4 + e] = (short)f2bf(b1[e]); }
            *(bf16x8*)&As[row][c0] = va;
            *(bf16x8*)&Bs[row][c0] = vb;
        }
        __syncthreads();

        bf16x8 af[4], bw[4];
        #pragma unroll
        for (int i = 0; i < 4; ++i) af[i] = *(const bf16x8*)&As[wm + i * 16 + ln][quad * 8];
        #pragma unroll
        for (int j = 0; j < 4; ++j) bw[j] = *(const bf16x8*)&Bs[wn + j * 16 + ln][quad * 8];
        #pragma unroll
        for (int i = 0; i < 4; ++i)
            #pragma unroll
            for (int j = 0; j < 4; ++j)
                acc[i][j] = __builtin_amdgcn_mfma_f32_16x16x32_bf16(af[i], bw[j], acc[i][j], 0, 0, 0);
    }

    if (ROPE) {
        #pragma unroll
        for (int i = 0; i < 4; ++i) {
            #pragma unroll
            for (int j = 0; j < 2; ++j) {
                int d = j * 16 + ln;
                float invf = exp2f(-(float)d * (13.287712379549449f / 32.0f));
                #pragma unroll
                for (int r = 0; r < 4; ++r) {
                    int mrow = rowBase + wm + i * 16 + quad * 4 + r;
                    int t = mrow & (T_SEQ - 1);
                    float fr = (float)t * invf;
                    float sn, cs;
                    sincosf(fr, &sn, &cs);
                    float a0 = acc[i][j][r], a2 = acc[i][j + 2][r];
                    acc[i][j][r]     = a0 * cs - a2 * sn;
                    acc[i][j + 2][r] = a2 * cs + a0 * sn;
                }
            }
        }
    }

    #pragma unroll
    for (int i = 0; i < 4; ++i) {
        int mrow = rowBase + wm + i * 16 + quad * 4;
        #pragma unroll
        for (int j = 0; j < 4; ++j) {
            int n = colBase + wn + j * 16 + ln;
            #pragma unroll
            for (int r = 0; r < 4; ++r) {
                if constexpr (OUTF32)
                    ((float*)Cv)[(size_t)(mrow + r) * N + n] = acc[i][j][r];
                else
                    ((u16*)Cv)[(size_t)(mrow + r) * N + n] = f2bf(acc[i][j][r]);
            }
        }
    }
}

// ===========================================================================
// V [B*T][KVDIM] -> Vt [B][KVDIM][T]
// ===========================================================================
__global__ __launch_bounds__(256) void transpose_v(const u16* __restrict__ V,
                                                   u16* __restrict__ Vt) {
    __shared__ __align__(16) u16 tile[32][33];
    const int x = threadIdx.x & 31;
    const int y = threadIdx.x >> 5;
    const int tok0 = blockIdx.y * 32;
    const int c0   = blockIdx.x * 32;
    #pragma unroll
    for (int yy = 0; yy < 32; yy += 8)
        tile[y + yy][x] = V[(size_t)(tok0 + y + yy) * KVDIM + c0 + x];
    __syncthreads();
    const int b  = tok0 >> 11;
    const int t0 = tok0 & (T_SEQ - 1);
    #pragma unroll
    for (int yy = 0; yy < 32; yy += 8)
        Vt[(size_t)(b * KVDIM + c0 + y + yy) * T_SEQ + t0 + x] = tile[x][y + yy];
}

// ===========================================================================
// Flash attention. grid = (T/128, NH, B), block = 256 (4 waves).
// Each wave: 32 queries as 2 row-groups of 16. 64-key tiles. 3 barriers/tile.
// Only the diagonal tile of each group is masked (block-uniform branch).
// ===========================================================================
__global__ __launch_bounds__(256) void attn(const u16* __restrict__ Q,
                                            const u16* __restrict__ Kx,
                                            const u16* __restrict__ Vt,
                                            u16* __restrict__ O) {
    __shared__ __align__(16) u16 Ks[64][72];          // [key][dim]
    __shared__ __align__(16) u16 Vs[64][72];          // [dim][key]
    __shared__ __align__(16) u16 Ps[2][4][16][72];    // [group][wave][q][key]

    const int tid  = threadIdx.x;
    const int lane = tid & 63;
    const int w    = tid >> 6;
    const int quad = lane >> 4;
    const int ln   = lane & 15;
    const int qblk = blockIdx.x;
    const int h    = blockIdx.y;
    const int b    = blockIdx.z;
    const int kvh  = h >> 2;
    const int qbase = qblk * 128;
    const int qr0[2] = { qbase + w * 16, qbase + 64 + w * 16 };

    bf16x8 aq[2][2];
    #pragma unroll
    for (int g = 0; g < 2; ++g) {
        const u16* qp = Q + (size_t)(b * T_SEQ + qr0[g] + ln) * DIMC + h * HDIM + quad * 8;
        aq[g][0] = *(const bf16x8*)qp;
        aq[g][1] = *(const bf16x8*)(qp + 32);
    }

    f32x4 o[2][4] = {};
    float mrun[2][4], lrun[2][4];
    #pragma unroll
    for (int g = 0; g < 2; ++g)
        #pragma unroll
        for (int r = 0; r < 4; ++r) { mrun[g][r] = -3.0e38f; lrun[g][r] = 0.0f; }

    // staging: row = tid>>2 (0..63), two bf16x8 at cols (tid&3)*16 and +8
    const int srow = tid >> 2;
    const int scol = (tid & 3) * 16;
    const u16* kbase = Kx + (size_t)(b * T_SEQ + srow) * KVDIM + kvh * HDIM + scol;
    const u16* vbase = Vt + (size_t)(b * KVDIM + kvh * HDIM + srow) * T_SEQ;

    const int ktmax = 2 * qblk + 1;
    const float scale = 0.125f;                 // 1/sqrt(64)
    const float L2E   = 1.4426950408889634f;

    for (int kt = 0; kt <= ktmax; ++kt) {
        const int k0 = kt * 64;
        __syncthreads();                         // Ks/Vs free to overwrite
        *(bf16x8*)&Ks[srow][scol]     = *(const bf16x8*)(kbase + (size_t)k0 * KVDIM);
        *(bf16x8*)&Ks[srow][scol + 8] = *(const bf16x8*)(kbase + (size_t)k0 * KVDIM + 8);
        *(bf16x8*)&Vs[srow][scol]     = *(const bf16x8*)(vbase + k0 + scol);
        *(bf16x8*)&Vs[srow][scol + 8] = *(const bf16x8*)(vbase + k0 + scol + 8);
        __syncthreads();                         // staging visible

        #pragma unroll
        for (int g = 0; g < 2; ++g) {
            if (kt > 2 * qblk + g) continue;     // group past its diagonal (uniform)
            const bool diag = (kt == 2 * qblk + g);
            f32x4 s[4];
            #pragma unroll
            for (int st = 0; st < 4; ++st) {
                f32x4 z = {};
                s[st] = __builtin_amdgcn_mfma_f32_16x16x32_bf16(
                            aq[g][0], *(const bf16x8*)&Ks[st * 16 + ln][quad * 8], z, 0, 0, 0);
                s[st] = __builtin_amdgcn_mfma_f32_16x16x32_bf16(
                            aq[g][1], *(const bf16x8*)&Ks[st * 16 + ln][32 + quad * 8], s[st], 0, 0, 0);
            }
            #pragma unroll
            for (int r = 0; r < 4; ++r) {
                const int qg = qr0[g] + quad * 4 + r;
                float v[4];
                #pragma unroll
                for (int st = 0; st < 4; ++st) {
                    v[st] = s[st][r] * scale;
                    if (diag && (k0 + st * 16 + ln > qg)) v[st] = -3.0e38f;
                }
                float mx = fmaxf(fmaxf(v[0], v[1]), fmaxf(v[2], v[3]));
                mx = fmaxf(mx, __shfl_xor(mx, 1));
                mx = fmaxf(mx, __shfl_xor(mx, 2));
                mx = fmaxf(mx, __shfl_xor(mx, 4));
                mx = fmaxf(mx, __shfl_xor(mx, 8));
                const float mnew  = fmaxf(mrun[g][r], mx);
                const float alpha = exp2f((mrun[g][r] - mnew) * L2E);
                float e[4], rs = 0.0f;
                #pragma unroll
                for (int st = 0; st < 4; ++st) { e[st] = exp2f((v[st] - mnew) * L2E); rs += e[st]; }
                rs += __shfl_xor(rs, 1);
                rs += __shfl_xor(rs, 2);
                rs += __shfl_xor(rs, 4);
                rs += __shfl_xor(rs, 8);
                lrun[g][r] = lrun[g][r] * alpha + rs;
                mrun[g][r] = mnew;
                #pragma unroll
                for (int t = 0; t < 4; ++t) o[g][t][r] *= alpha;
                #pragma unroll
                for (int st = 0; st < 4; ++st)
                    Ps[g][w][quad * 4 + r][st * 16 + ln] = f2bf(e[st]);
            }
        }
        __syncthreads();                         // P visible (cheap: uniform)

        #pragma unroll
        for (int g = 0; g < 2; ++g) {
            if (kt > 2 * qblk + g) continue;
            bf16x8 pa0 = *(const bf16x8*)&Ps[g][w][ln][quad * 8];
            bf16x8 pa1 = *(const bf16x8*)&Ps[g][w][ln][32 + quad * 8];
            #pragma unroll
            for (int t = 0; t < 4; ++t) {
                o[g][t] = __builtin_amdgcn_mfma_f32_16x16x32_bf16(
                              pa0, *(const bf16x8*)&Vs[t * 16 + ln][quad * 8], o[g][t], 0, 0, 0);
                o[g][t] = __builtin_amdgcn_mfma_f32_16x16x32_bf16(
                              pa1, *(const bf16x8*)&Vs[t * 16 + ln][32 + quad * 8], o[g][t], 0, 0, 0);
            }
        }
    }

    #pragma unroll
    for (int g = 0; g < 2; ++g) {
        #pragma unroll
        for (int r = 0; r < 4; ++r) {
            float inv = 1.0f / lrun[g][r];
            size_t obase = (size_t)(b * T_SEQ + qr0[g] + quad * 4 + r) * DIMC + h * HDIM;
            #pragma unroll
            for (int t = 0; t < 4; ++t)
                O[obase + t * 16 + ln] = f2bf(o[g][t][r] * inv);
        }
    }
}

// ===========================================================================
extern "C" void kernel_launch(void* const* d_in, const int* in_sizes, int n_in,
                              void* d_out, int out_size, void* d_ws, size_t ws_size,
                              hipStream_t stream) {
    const float* x  = (const float*)d_in[0];
    const float* wq = (const float*)d_in[1];
    const float* wk = (const float*)d_in[2];
    const float* wv = (const float*)d_in[3];
    const float* wo = (const float*)d_in[4];
    float* out = (float*)d_out;

    char* ws = (char*)d_ws;
    constexpr size_t MB = 1024 * 1024;
    u16* Qb  = (u16*)(ws);             // 16 MB [4096][2048]
    u16* Kb  = (u16*)(ws + 16 * MB);   //  4 MB [4096][512]
    u16* Vb  = (u16*)(ws + 20 * MB);   //  4 MB [4096][512]
    u16* Vtb = (u16*)(ws + 24 * MB);   //  4 MB [2][512][2048]
    u16* AOb = (u16*)(ws + 28 * MB);   // 16 MB [4096][2048]  (fast path: aliases xb)
    const int M = BATCH * T_SEQ;       // 4096

    const bool fast = (ws_size >= 64 * MB);
    if (fast) {
        u16* xb  = AOb;                     // x dead before attn writes AOb
        u16* wqb = (u16*)(ws + 44 * MB);    // 8 MB
        u16* wkb = (u16*)(ws + 52 * MB);    // 2 MB
        u16* wvb = (u16*)(ws + 54 * MB);    // 2 MB
        u16* wob = (u16*)(ws + 56 * MB);    // 8 MB
        hipLaunchKernelGGL(cvt_bf16, dim3(1024), dim3(256), 0, stream, x,  xb,  M * DIMC);
        hipLaunchKernelGGL(cvt_bf16, dim3(1024), dim3(256), 0, stream, wq, wqb, DIMC * DIMC);
        hipLaunchKernelGGL(cvt_bf16, dim3(512),  dim3(256), 0, stream, wk, wkb, KVDIM * DIMC);
        hipLaunchKernelGGL(cvt_bf16, dim3(512),  dim3(256), 0, stream, wv, wvb, KVDIM * DIMC);
        hipLaunchKernelGGL(cvt_bf16, dim3(1024), dim3(256), 0, stream, wo, wob, DIMC * DIMC);
        hipLaunchKernelGGL(qkv_gemm, dim3(24, M / 128), dim3(256), 0, stream,
                           xb, wqb, wkb, wvb, Qb, Kb, Vb);
        hipLaunchKernelGGL(transpose_v, dim3(KVDIM / 32, M / 32), dim3(256), 0, stream, Vb, Vtb);
        hipLaunchKernelGGL(attn, dim3(T_SEQ / 128, NHEAD, BATCH), dim3(256), 0, stream,
                           Qb, Kb, Vtb, AOb);
        hipLaunchKernelGGL(gemm_f32out, dim3(DIMC / 128, M / 128), dim3(256), 0, stream,
                           AOb, wob, out, DIMC, DIMC);
    } else {
        hipLaunchKernelGGL((gemm_bt<true, true, false>),  dim3(DIMC / 128, M / 128),  dim3(256), 0, stream,
                           x, wq, Qb, M, DIMC, DIMC);
        hipLaunchKernelGGL((gemm_bt<true, true, false>),  dim3(KVDIM / 128, M / 128), dim3(256), 0, stream,
                           x, wk, Kb, M, KVDIM, DIMC);
        hipLaunchKernelGGL((gemm_bt<false, true, false>), dim3(KVDIM / 128, M / 128), dim3(256), 0, stream,
                           x, wv, Vb, M, KVDIM, DIMC);
        hipLaunchKernelGGL(transpose_v, dim3(KVDIM / 32, M / 32), dim3(256), 0, stream, Vb, Vtb);
        hipLaunchKernelGGL(attn, dim3(T_SEQ / 128, NHEAD, BATCH), dim3(256), 0, stream,
                           Qb, Kb, Vtb, AOb);
        hipLaunchKernelGGL((gemm_bt<false, false, true>), dim3(DIMC / 128, M / 128), dim3(256), 0, stream,
                           AOb, wo, out, M, DIMC, DIMC);
    }
}

// Round 4
// 404.752 us; speedup vs baseline: 1.8930x; 1.4488x over previous
//
#include <hip/hip_runtime.h>

// Attention_6219112645023 — fp32 in / fp32 out, bf16 internal compute (MFMA).
// B=2, T=2048, DIM=2048, NH=32, NKV=8, HD=64. Causal GQA + RoPE + projections.
// Pipeline: cvt5 -> fused QKV gemm (global_load_lds) -> transpose(V) ->
// flash attn (balanced qt pairs, shuffle-free softmax) -> O gemm.
// Workspace: 64 MB. xb aliases AOb (x dead before attn writes it).

typedef unsigned short u16;
typedef __attribute__((ext_vector_type(8))) short bf16x8;  // 8 bf16 in 4 VGPRs
typedef __attribute__((ext_vector_type(4))) float f32x4;
typedef __attribute__((ext_vector_type(4))) unsigned short u16x4;

constexpr int T_SEQ = 2048;
constexpr int DIMC  = 2048;
constexpr int NHEAD = 32;
constexpr int HDIM  = 64;
constexpr int KVDIM = 512;   // NKV * HDIM
constexpr int BATCH = 2;

__device__ __forceinline__ u16 f2bf(float f) {
    union { float f; unsigned int i; } v; v.f = f;
    unsigned int r = v.i + 0x7FFFu + ((v.i >> 16) & 1u);   // RNE
    return (u16)(r >> 16);
}

typedef __attribute__((address_space(1))) unsigned int as1_uint;
typedef __attribute__((address_space(3))) unsigned int as3_uint;
__device__ __forceinline__ void glds16(const u16* g, u16* l) {
    // async global->LDS, 16B/lane; LDS dest = wave-uniform base + lane*16
    __builtin_amdgcn_global_load_lds((as1_uint*)(u16*)g, (as3_uint*)l, 16, 0, 0);
}

// ===========================================================================
// Fused fp32->bf16 convert of all 5 inputs (one launch).
// ===========================================================================
__global__ __launch_bounds__(256) void cvt5(const float* __restrict__ x,
                                            const float* __restrict__ wq,
                                            const float* __restrict__ wk,
                                            const float* __restrict__ wv,
                                            const float* __restrict__ wo,
                                            u16* __restrict__ xb,  u16* __restrict__ wqb,
                                            u16* __restrict__ wkb, u16* __restrict__ wvb,
                                            u16* __restrict__ wob) {
    constexpr int E0 = BATCH * T_SEQ * DIMC;          // 8388608
    constexpr int E1 = E0 + DIMC * DIMC;              // +4194304
    constexpr int E2 = E1 + KVDIM * DIMC;             // +1048576
    constexpr int E3 = E2 + KVDIM * DIMC;             // +1048576
    constexpr int E4 = E3 + DIMC * DIMC;              // 18874368 total
    for (int i = (blockIdx.x * 256 + threadIdx.x) * 4; i < E4; i += gridDim.x * 1024) {
        const float* s; u16* d; int off;
        if (i < E0)      { s = x;  d = xb;  off = 0;  }
        else if (i < E1) { s = wq; d = wqb; off = E0; }
        else if (i < E2) { s = wk; d = wkb; off = E1; }
        else if (i < E3) { s = wv; d = wvb; off = E2; }
        else             { s = wo; d = wob; off = E3; }
        f32x4 v = *(const f32x4*)(s + (i - off));
        u16x4 o;
        #pragma unroll
        for (int e = 0; e < 4; ++e) o[e] = f2bf(v[e]);
        *(u16x4*)(d + (i - off)) = o;
    }
}

// ===========================================================================
// m97-style GEMM core: C = A[M][K] . W[N][K]^T, bf16 in, global_load_lds
// staging into unpadded LDS, 128x128 tile, BK=32, 4 waves x 4x4 mfma tiles.
// rope (runtime, block-uniform): fused rotary on 64-col head spans.
// ===========================================================================
template <bool OUTF32>
__device__ __forceinline__ void gemm_core(const u16* __restrict__ A,
                                          const u16* __restrict__ W,
                                          void* __restrict__ Cv,
                                          int rowBase, int colBase,
                                          int N, int K, bool rope) {
    __shared__ __align__(16) u16 As[128 * 32];   // unpadded: glds lane order
    __shared__ __align__(16) u16 Bs[128 * 32];

    const int tid  = threadIdx.x;
    const int lane = tid & 63;
    const int w    = tid >> 6;
    const int quad = lane >> 4;
    const int ln   = lane & 15;
    const int wm = (w >> 1) * 64;
    const int wn = (w & 1) * 64;

    f32x4 acc[4][4] = {};

    // staging: chunk c = 16 rows; lane i -> row c*16 + (i>>2), col (i&3)*8
    const int srow = lane >> 2;
    const int scol = (lane & 3) * 8;
    const u16* aC0 = A + (size_t)(rowBase + w * 16 + srow) * K + scol;
    const u16* aC1 = A + (size_t)(rowBase + (w + 4) * 16 + srow) * K + scol;
    const u16* bC0 = W + (size_t)(colBase + w * 16 + srow) * K + scol;
    const u16* bC1 = W + (size_t)(colBase + (w + 4) * 16 + srow) * K + scol;
    u16* asl0 = As + w * 512;
    u16* asl1 = As + (w + 4) * 512;
    u16* bsl0 = Bs + w * 512;
    u16* bsl1 = Bs + (w + 4) * 512;

    for (int kk = 0; kk < K; kk += 32) {
        __syncthreads();
        glds16(aC0 + kk, asl0);
        glds16(aC1 + kk, asl1);
        glds16(bC0 + kk, bsl0);
        glds16(bC1 + kk, bsl1);
        __syncthreads();   // vmcnt(0) drain -> staged data visible

        bf16x8 af[4], bw[4];
        #pragma unroll
        for (int i = 0; i < 4; ++i) af[i] = *(const bf16x8*)(As + (wm + i * 16 + ln) * 32 + quad * 8);
        #pragma unroll
        for (int j = 0; j < 4; ++j) bw[j] = *(const bf16x8*)(Bs + (wn + j * 16 + ln) * 32 + quad * 8);
        #pragma unroll
        for (int i = 0; i < 4; ++i)
            #pragma unroll
            for (int j = 0; j < 4; ++j)
                acc[i][j] = __builtin_amdgcn_mfma_f32_16x16x32_bf16(af[i], bw[j], acc[i][j], 0, 0, 0);
    }

    if (rope) {
        // head-local d = (colBase+wn+j*16+ln) % 64 = j*16+ln
        #pragma unroll
        for (int i = 0; i < 4; ++i) {
            #pragma unroll
            for (int j = 0; j < 2; ++j) {
                int d = j * 16 + ln;
                float invf = exp2f(-(float)d * (13.287712379549449f / 32.0f));
                #pragma unroll
                for (int r = 0; r < 4; ++r) {
                    int mrow = rowBase + wm + i * 16 + quad * 4 + r;
                    int t = mrow & (T_SEQ - 1);
                    float fr = (float)t * invf;
                    float sn, cs;
                    sincosf(fr, &sn, &cs);
                    float a0 = acc[i][j][r], a2 = acc[i][j + 2][r];
                    acc[i][j][r]     = a0 * cs - a2 * sn;
                    acc[i][j + 2][r] = a2 * cs + a0 * sn;
                }
            }
        }
    }

    #pragma unroll
    for (int i = 0; i < 4; ++i) {
        int mrow = rowBase + wm + i * 16 + quad * 4;
        #pragma unroll
        for (int j = 0; j < 4; ++j) {
            int n = colBase + wn + j * 16 + ln;
            #pragma unroll
            for (int r = 0; r < 4; ++r) {
                if constexpr (OUTF32)
                    ((float*)Cv)[(size_t)(mrow + r) * N + n] = acc[i][j][r];
                else
                    ((u16*)Cv)[(size_t)(mrow + r) * N + n] = f2bf(acc[i][j][r]);
            }
        }
    }
}

// Fused QKV: grid.x 0..23 -> Q cols (16 blks) | K cols (4) | V cols (4)
__global__ __launch_bounds__(256) void qkv_gemm(const u16* __restrict__ xb,
                                                const u16* __restrict__ wqb,
                                                const u16* __restrict__ wkb,
                                                const u16* __restrict__ wvb,
                                                u16* __restrict__ Qb,
                                                u16* __restrict__ Kb,
                                                u16* __restrict__ Vb) {
    const int nb = blockIdx.x;
    const int rowBase = blockIdx.y * 128;
    const u16* W; u16* C; int colBase, N; bool rope;
    if (nb < 16)      { W = wqb; C = Qb; colBase = nb * 128;        N = DIMC;  rope = true; }
    else if (nb < 20) { W = wkb; C = Kb; colBase = (nb - 16) * 128; N = KVDIM; rope = true; }
    else              { W = wvb; C = Vb; colBase = (nb - 20) * 128; N = KVDIM; rope = false; }
    gemm_core<false>(xb, W, C, rowBase, colBase, N, DIMC, rope);
}

__global__ __launch_bounds__(256) void gemm_f32out(const u16* __restrict__ A,
                                                   const u16* __restrict__ W,
                                                   float* __restrict__ C,
                                                   int N, int K) {
    gemm_core<true>(A, W, C, blockIdx.y * 128, blockIdx.x * 128, N, K, false);
}

// ===========================================================================
// V [B*T][KVDIM] -> Vt [B][KVDIM][T]
// ===========================================================================
__global__ __launch_bounds__(256) void transpose_v(const u16* __restrict__ V,
                                                   u16* __restrict__ Vt) {
    __shared__ __align__(16) u16 tile[32][33];
    const int x = threadIdx.x & 31;
    const int y = threadIdx.x >> 5;
    const int tok0 = blockIdx.y * 32;
    const int c0   = blockIdx.x * 32;
    #pragma unroll
    for (int yy = 0; yy < 32; yy += 8)
        tile[y + yy][x] = V[(size_t)(tok0 + y + yy) * KVDIM + c0 + x];
    __syncthreads();
    const int b  = tok0 >> 11;
    const int t0 = tok0 & (T_SEQ - 1);
    #pragma unroll
    for (int yy = 0; yy < 32; yy += 8)
        Vt[(size_t)(b * KVDIM + c0 + y + yy) * T_SEQ + t0 + x] = tile[x][y + yy];
}

// ===========================================================================
// Flash attention. grid = (8, NH, B), block = 256 (4 waves).
// Each block processes query tiles qt = blockIdx.x and 15-blockIdx.x
// sequentially -> 34 key-tiles per block, perfectly uniform load.
// Softmax: fixed shift M0=8 (no running max, no rescale, no per-tile
// shuffles); per-lane partial l reduced once in the epilogue.
// P exchange is wave-private LDS: s_waitcnt lgkmcnt(0), no barrier.
// ===========================================================================
__global__ __launch_bounds__(256) void attn(const u16* __restrict__ Q,
                                            const u16* __restrict__ Kx,
                                            const u16* __restrict__ Vt,
                                            u16* __restrict__ O) {
    __shared__ __align__(16) u16 Ks[64][72];          // [key][dim]
    __shared__ __align__(16) u16 Vs[64][72];          // [dim][key]
    __shared__ __align__(16) u16 Ps[2][4][16][72];    // [group][wave][q][key]

    const int tid  = threadIdx.x;
    const int lane = tid & 63;
    const int w    = tid >> 6;
    const int quad = lane >> 4;
    const int ln   = lane & 15;
    const int h    = blockIdx.y;
    const int b    = blockIdx.z;
    const int kvh  = h >> 2;

    // staging: row = tid>>2 (0..63), two bf16x8 at cols (tid&3)*16 and +8
    const int srow = tid >> 2;
    const int scol = (tid & 3) * 16;
    const u16* kbase = Kx + (size_t)(b * T_SEQ + srow) * KVDIM + kvh * HDIM + scol;
    const u16* vbase = Vt + (size_t)(b * KVDIM + kvh * HDIM + srow) * T_SEQ;

    const float K1 = 0.125f * 1.4426950408889634f;   // scale * log2(e)
    const float K2 = 8.0f * 1.4426950408889634f;     // M0 * log2(e)

    #pragma unroll
    for (int phase = 0; phase < 2; ++phase) {
        const int qt = phase ? (15 - (int)blockIdx.x) : (int)blockIdx.x;
        const int qbase = qt * 128;
        const int qr0[2] = { qbase + w * 16, qbase + 64 + w * 16 };

        bf16x8 aq[2][2];
        #pragma unroll
        for (int g = 0; g < 2; ++g) {
            const u16* qp = Q + (size_t)(b * T_SEQ + qr0[g] + ln) * DIMC + h * HDIM + quad * 8;
            aq[g][0] = *(const bf16x8*)qp;
            aq[g][1] = *(const bf16x8*)(qp + 32);
        }

        f32x4 o[2][4] = {};
        float lpart[2][4] = {};

        const int ktmax = 2 * qt + 1;
        for (int kt = 0; kt <= ktmax; ++kt) {
            const int k0 = kt * 64;
            __syncthreads();                         // Ks/Vs free to overwrite
            *(bf16x8*)&Ks[srow][scol]     = *(const bf16x8*)(kbase + (size_t)k0 * KVDIM);
            *(bf16x8*)&Ks[srow][scol + 8] = *(const bf16x8*)(kbase + (size_t)k0 * KVDIM + 8);
            *(bf16x8*)&Vs[srow][scol]     = *(const bf16x8*)(vbase + k0 + scol);
            *(bf16x8*)&Vs[srow][scol + 8] = *(const bf16x8*)(vbase + k0 + scol + 8);
            __syncthreads();                         // staging visible

            #pragma unroll
            for (int g = 0; g < 2; ++g) {
                if (kt > 2 * qt + g) continue;       // uniform: only filters g=0 at last kt
                const bool diag = (kt == 2 * qt + g);
                f32x4 s[4];
                #pragma unroll
                for (int st = 0; st < 4; ++st) {
                    f32x4 z = {};
                    s[st] = __builtin_amdgcn_mfma_f32_16x16x32_bf16(
                                aq[g][0], *(const bf16x8*)&Ks[st * 16 + ln][quad * 8], z, 0, 0, 0);
                    s[st] = __builtin_amdgcn_mfma_f32_16x16x32_bf16(
                                aq[g][1], *(const bf16x8*)&Ks[st * 16 + ln][32 + quad * 8], s[st], 0, 0, 0);
                }
                #pragma unroll
                for (int r = 0; r < 4; ++r) {
                    const int qg = qr0[g] + quad * 4 + r;
                    float e[4], rs = 0.0f;
                    #pragma unroll
                    for (int st = 0; st < 4; ++st) {
                        bool masked = diag && (k0 + st * 16 + ln > qg);
                        e[st] = masked ? 0.0f : exp2f(fmaf(s[st][r], K1, -K2));
                        rs += e[st];
                    }
                    lpart[g][r] += rs;
                    #pragma unroll
                    for (int st = 0; st < 4; ++st)
                        Ps[g][w][quad * 4 + r][st * 16 + ln] = f2bf(e[st]);
                }
            }
            // P exchange is wave-private: DS in-order per wave; fence the
            // compiler and drain lgkm before cross-lane reads.
            __asm__ __volatile__("s_waitcnt lgkmcnt(0)" ::: "memory");

            #pragma unroll
            for (int g = 0; g < 2; ++g) {
                if (kt > 2 * qt + g) continue;
                bf16x8 pa0 = *(const bf16x8*)&Ps[g][w][ln][quad * 8];
                bf16x8 pa1 = *(const bf16x8*)&Ps[g][w][ln][32 + quad * 8];
                #pragma unroll
                for (int t = 0; t < 4; ++t) {
                    o[g][t] = __builtin_amdgcn_mfma_f32_16x16x32_bf16(
                                  pa0, *(const bf16x8*)&Vs[t * 16 + ln][quad * 8], o[g][t], 0, 0, 0);
                    o[g][t] = __builtin_amdgcn_mfma_f32_16x16x32_bf16(
                                  pa1, *(const bf16x8*)&Vs[t * 16 + ln][32 + quad * 8], o[g][t], 0, 0, 0);
                }
            }
        }

        // epilogue: one cross-lane reduction of l per (g,r), normalize, store
        #pragma unroll
        for (int g = 0; g < 2; ++g) {
            #pragma unroll
            for (int r = 0; r < 4; ++r) {
                float rs = lpart[g][r];
                rs += __shfl_xor(rs, 1);
                rs += __shfl_xor(rs, 2);
                rs += __shfl_xor(rs, 4);
                rs += __shfl_xor(rs, 8);
                float inv = 1.0f / rs;
                size_t obase = (size_t)(b * T_SEQ + qr0[g] + quad * 4 + r) * DIMC + h * HDIM;
                #pragma unroll
                for (int t = 0; t < 4; ++t)
                    O[obase + t * 16 + ln] = f2bf(o[g][t][r] * inv);
            }
        }
    }
}

// ===========================================================================
extern "C" void kernel_launch(void* const* d_in, const int* in_sizes, int n_in,
                              void* d_out, int out_size, void* d_ws, size_t ws_size,
                              hipStream_t stream) {
    const float* x  = (const float*)d_in[0];
    const float* wq = (const float*)d_in[1];
    const float* wk = (const float*)d_in[2];
    const float* wv = (const float*)d_in[3];
    const float* wo = (const float*)d_in[4];
    float* out = (float*)d_out;

    char* ws = (char*)d_ws;
    constexpr size_t MB = 1024 * 1024;
    u16* Qb  = (u16*)(ws);             // 16 MB [4096][2048]
    u16* Kb  = (u16*)(ws + 16 * MB);   //  4 MB [4096][512]
    u16* Vb  = (u16*)(ws + 20 * MB);   //  4 MB [4096][512]
    u16* Vtb = (u16*)(ws + 24 * MB);   //  4 MB [2][512][2048]
    u16* AOb = (u16*)(ws + 28 * MB);   // 16 MB [4096][2048]  (aliases xb)
    u16* xb  = AOb;                    // x dead before attn writes AOb
    u16* wqb = (u16*)(ws + 44 * MB);   //  8 MB
    u16* wkb = (u16*)(ws + 52 * MB);   //  2 MB
    u16* wvb = (u16*)(ws + 54 * MB);   //  2 MB
    u16* wob = (u16*)(ws + 56 * MB);   //  8 MB
    const int M = BATCH * T_SEQ;       // 4096

    hipLaunchKernelGGL(cvt5, dim3(2048), dim3(256), 0, stream,
                       x, wq, wk, wv, wo, xb, wqb, wkb, wvb, wob);
    hipLaunchKernelGGL(qkv_gemm, dim3(24, M / 128), dim3(256), 0, stream,
                       xb, wqb, wkb, wvb, Qb, Kb, Vb);
    hipLaunchKernelGGL(transpose_v, dim3(KVDIM / 32, M / 32), dim3(256), 0, stream, Vb, Vtb);
    hipLaunchKernelGGL(attn, dim3(8, NHEAD, BATCH), dim3(256), 0, stream,
                       Qb, Kb, Vtb, AOb);
    hipLaunchKernelGGL(gemm_f32out, dim3(DIMC / 128, M / 128), dim3(256), 0, stream,
                       AOb, wob, out, DIMC, DIMC);
}

// Round 5
// 359.585 us; speedup vs baseline: 2.1308x; 1.1256x over previous
//
#include <hip/hip_runtime.h>

// Attention_6219112645023 — fp32 in / fp32 out, bf16 internal compute (MFMA).
// B=2, T=2048, DIM=2048, NH=32, NKV=8, HD=64. Causal GQA + RoPE + projections.
// Pipeline: cvt5 -> fused QKV gemm (global_load_lds) -> transpose(V) ->
// flash attn (balanced qt pairs, shuffle-free softmax) -> O gemm.
// Workspace: 64 MB. xb aliases AOb (x dead before attn writes it).
// R5: __launch_bounds__(256,4) on GEMMs (VGPR<=128 -> 4 blocks/CU) + reduced
// fragment liveness (af loaded per-i) to hide the barrier/vmcnt drain.

typedef unsigned short u16;
typedef __attribute__((ext_vector_type(8))) short bf16x8;  // 8 bf16 in 4 VGPRs
typedef __attribute__((ext_vector_type(4))) float f32x4;
typedef __attribute__((ext_vector_type(4))) unsigned short u16x4;

constexpr int T_SEQ = 2048;
constexpr int DIMC  = 2048;
constexpr int NHEAD = 32;
constexpr int HDIM  = 64;
constexpr int KVDIM = 512;   // NKV * HDIM
constexpr int BATCH = 2;

__device__ __forceinline__ u16 f2bf(float f) {
    union { float f; unsigned int i; } v; v.f = f;
    unsigned int r = v.i + 0x7FFFu + ((v.i >> 16) & 1u);   // RNE
    return (u16)(r >> 16);
}

typedef __attribute__((address_space(1))) unsigned int as1_uint;
typedef __attribute__((address_space(3))) unsigned int as3_uint;
__device__ __forceinline__ void glds16(const u16* g, u16* l) {
    // async global->LDS, 16B/lane; LDS dest = wave-uniform base + lane*16
    __builtin_amdgcn_global_load_lds((as1_uint*)(u16*)g, (as3_uint*)l, 16, 0, 0);
}

// ===========================================================================
// Fused fp32->bf16 convert of all 5 inputs (one launch).
// ===========================================================================
__global__ __launch_bounds__(256) void cvt5(const float* __restrict__ x,
                                            const float* __restrict__ wq,
                                            const float* __restrict__ wk,
                                            const float* __restrict__ wv,
                                            const float* __restrict__ wo,
                                            u16* __restrict__ xb,  u16* __restrict__ wqb,
                                            u16* __restrict__ wkb, u16* __restrict__ wvb,
                                            u16* __restrict__ wob) {
    constexpr int E0 = BATCH * T_SEQ * DIMC;          // 8388608
    constexpr int E1 = E0 + DIMC * DIMC;              // +4194304
    constexpr int E2 = E1 + KVDIM * DIMC;             // +1048576
    constexpr int E3 = E2 + KVDIM * DIMC;             // +1048576
    constexpr int E4 = E3 + DIMC * DIMC;              // 18874368 total
    for (int i = (blockIdx.x * 256 + threadIdx.x) * 4; i < E4; i += gridDim.x * 1024) {
        const float* s; u16* d; int off;
        if (i < E0)      { s = x;  d = xb;  off = 0;  }
        else if (i < E1) { s = wq; d = wqb; off = E0; }
        else if (i < E2) { s = wk; d = wkb; off = E1; }
        else if (i < E3) { s = wv; d = wvb; off = E2; }
        else             { s = wo; d = wob; off = E3; }
        f32x4 v = *(const f32x4*)(s + (i - off));
        u16x4 o;
        #pragma unroll
        for (int e = 0; e < 4; ++e) o[e] = f2bf(v[e]);
        *(u16x4*)(d + (i - off)) = o;
    }
}

// ===========================================================================
// m97-style GEMM core: C = A[M][K] . W[N][K]^T, bf16 in, global_load_lds
// staging into unpadded LDS, 128x128 tile, BK=32, 4 waves x 4x4 mfma tiles.
// rope (runtime, block-uniform): fused rotary on 64-col head spans.
// Register budget: acc 64 + bw 32 + af 8 + staging ~20 -> fits 128 VGPR
// (4 waves/SIMD with __launch_bounds__(256,4)).
// ===========================================================================
template <bool OUTF32>
__device__ __forceinline__ void gemm_core(const u16* __restrict__ A,
                                          const u16* __restrict__ W,
                                          void* __restrict__ Cv,
                                          int rowBase, int colBase,
                                          int N, int K, bool rope) {
    __shared__ __align__(16) u16 As[128 * 32];   // unpadded: glds lane order
    __shared__ __align__(16) u16 Bs[128 * 32];

    const int tid  = threadIdx.x;
    const int lane = tid & 63;
    const int w    = tid >> 6;
    const int quad = lane >> 4;
    const int ln   = lane & 15;
    const int wm = (w >> 1) * 64;
    const int wn = (w & 1) * 64;

    f32x4 acc[4][4] = {};

    // staging: chunk c = 16 rows; lane i -> row c*16 + (i>>2), col (i&3)*8
    const int srow = lane >> 2;
    const int scol = (lane & 3) * 8;
    const u16* aC0 = A + (size_t)(rowBase + w * 16 + srow) * K + scol;
    const u16* aC1 = A + (size_t)(rowBase + (w + 4) * 16 + srow) * K + scol;
    const u16* bC0 = W + (size_t)(colBase + w * 16 + srow) * K + scol;
    const u16* bC1 = W + (size_t)(colBase + (w + 4) * 16 + srow) * K + scol;
    u16* asl0 = As + w * 512;
    u16* asl1 = As + (w + 4) * 512;
    u16* bsl0 = Bs + w * 512;
    u16* bsl1 = Bs + (w + 4) * 512;

    for (int kk = 0; kk < K; kk += 32) {
        __syncthreads();
        glds16(aC0 + kk, asl0);
        glds16(aC1 + kk, asl1);
        glds16(bC0 + kk, bsl0);
        glds16(bC1 + kk, bsl1);
        __syncthreads();   // vmcnt(0) drain -> staged data visible

        bf16x8 bw[4];
        #pragma unroll
        for (int j = 0; j < 4; ++j) bw[j] = *(const bf16x8*)(Bs + (wn + j * 16 + ln) * 32 + quad * 8);
        #pragma unroll
        for (int i = 0; i < 4; ++i) {
            bf16x8 af = *(const bf16x8*)(As + (wm + i * 16 + ln) * 32 + quad * 8);
            #pragma unroll
            for (int j = 0; j < 4; ++j)
                acc[i][j] = __builtin_amdgcn_mfma_f32_16x16x32_bf16(af, bw[j], acc[i][j], 0, 0, 0);
        }
    }

    if (rope) {
        // head-local d = (colBase+wn+j*16+ln) % 64 = j*16+ln
        #pragma unroll
        for (int i = 0; i < 4; ++i) {
            #pragma unroll
            for (int j = 0; j < 2; ++j) {
                int d = j * 16 + ln;
                float invf = exp2f(-(float)d * (13.287712379549449f / 32.0f));
                #pragma unroll
                for (int r = 0; r < 4; ++r) {
                    int mrow = rowBase + wm + i * 16 + quad * 4 + r;
                    int t = mrow & (T_SEQ - 1);
                    float fr = (float)t * invf;
                    float sn, cs;
                    sincosf(fr, &sn, &cs);
                    float a0 = acc[i][j][r], a2 = acc[i][j + 2][r];
                    acc[i][j][r]     = a0 * cs - a2 * sn;
                    acc[i][j + 2][r] = a2 * cs + a0 * sn;
                }
            }
        }
    }

    #pragma unroll
    for (int i = 0; i < 4; ++i) {
        int mrow = rowBase + wm + i * 16 + quad * 4;
        #pragma unroll
        for (int j = 0; j < 4; ++j) {
            int n = colBase + wn + j * 16 + ln;
            #pragma unroll
            for (int r = 0; r < 4; ++r) {
                if constexpr (OUTF32)
                    ((float*)Cv)[(size_t)(mrow + r) * N + n] = acc[i][j][r];
                else
                    ((u16*)Cv)[(size_t)(mrow + r) * N + n] = f2bf(acc[i][j][r]);
            }
        }
    }
}

// Fused QKV: grid.x 0..23 -> Q cols (16 blks) | K cols (4) | V cols (4)
__global__ __launch_bounds__(256, 4) void qkv_gemm(const u16* __restrict__ xb,
                                                   const u16* __restrict__ wqb,
                                                   const u16* __restrict__ wkb,
                                                   const u16* __restrict__ wvb,
                                                   u16* __restrict__ Qb,
                                                   u16* __restrict__ Kb,
                                                   u16* __restrict__ Vb) {
    const int nb = blockIdx.x;
    const int rowBase = blockIdx.y * 128;
    const u16* W; u16* C; int colBase, N; bool rope;
    if (nb < 16)      { W = wqb; C = Qb; colBase = nb * 128;        N = DIMC;  rope = true; }
    else if (nb < 20) { W = wkb; C = Kb; colBase = (nb - 16) * 128; N = KVDIM; rope = true; }
    else              { W = wvb; C = Vb; colBase = (nb - 20) * 128; N = KVDIM; rope = false; }
    gemm_core<false>(xb, W, C, rowBase, colBase, N, DIMC, rope);
}

__global__ __launch_bounds__(256, 4) void gemm_f32out(const u16* __restrict__ A,
                                                      const u16* __restrict__ W,
                                                      float* __restrict__ C,
                                                      int N, int K) {
    gemm_core<true>(A, W, C, blockIdx.y * 128, blockIdx.x * 128, N, K, false);
}

// ===========================================================================
// V [B*T][KVDIM] -> Vt [B][KVDIM][T]
// ===========================================================================
__global__ __launch_bounds__(256) void transpose_v(const u16* __restrict__ V,
                                                   u16* __restrict__ Vt) {
    __shared__ __align__(16) u16 tile[32][33];
    const int x = threadIdx.x & 31;
    const int y = threadIdx.x >> 5;
    const int tok0 = blockIdx.y * 32;
    const int c0   = blockIdx.x * 32;
    #pragma unroll
    for (int yy = 0; yy < 32; yy += 8)
        tile[y + yy][x] = V[(size_t)(tok0 + y + yy) * KVDIM + c0 + x];
    __syncthreads();
    const int b  = tok0 >> 11;
    const int t0 = tok0 & (T_SEQ - 1);
    #pragma unroll
    for (int yy = 0; yy < 32; yy += 8)
        Vt[(size_t)(b * KVDIM + c0 + y + yy) * T_SEQ + t0 + x] = tile[x][y + yy];
}

// ===========================================================================
// Flash attention. grid = (8, NH, B), block = 256 (4 waves).
// Each block processes query tiles qt = blockIdx.x and 15-blockIdx.x
// sequentially -> 34 key-tiles per block, perfectly uniform load.
// Softmax: fixed shift M0=8 (no running max, no rescale, no per-tile
// shuffles); per-lane partial l reduced once in the epilogue.
// P exchange is wave-private LDS: s_waitcnt lgkmcnt(0), no barrier.
// ===========================================================================
__global__ __launch_bounds__(256) void attn(const u16* __restrict__ Q,
                                            const u16* __restrict__ Kx,
                                            const u16* __restrict__ Vt,
                                            u16* __restrict__ O) {
    __shared__ __align__(16) u16 Ks[64][72];          // [key][dim]
    __shared__ __align__(16) u16 Vs[64][72];          // [dim][key]
    __shared__ __align__(16) u16 Ps[2][4][16][72];    // [group][wave][q][key]

    const int tid  = threadIdx.x;
    const int lane = tid & 63;
    const int w    = tid >> 6;
    const int quad = lane >> 4;
    const int ln   = lane & 15;
    const int h    = blockIdx.y;
    const int b    = blockIdx.z;
    const int kvh  = h >> 2;

    // staging: row = tid>>2 (0..63), two bf16x8 at cols (tid&3)*16 and +8
    const int srow = tid >> 2;
    const int scol = (tid & 3) * 16;
    const u16* kbase = Kx + (size_t)(b * T_SEQ + srow) * KVDIM + kvh * HDIM + scol;
    const u16* vbase = Vt + (size_t)(b * KVDIM + kvh * HDIM + srow) * T_SEQ;

    const float K1 = 0.125f * 1.4426950408889634f;   // scale * log2(e)
    const float K2 = 8.0f * 1.4426950408889634f;     // M0 * log2(e)

    #pragma unroll
    for (int phase = 0; phase < 2; ++phase) {
        const int qt = phase ? (15 - (int)blockIdx.x) : (int)blockIdx.x;
        const int qbase = qt * 128;
        const int qr0[2] = { qbase + w * 16, qbase + 64 + w * 16 };

        bf16x8 aq[2][2];
        #pragma unroll
        for (int g = 0; g < 2; ++g) {
            const u16* qp = Q + (size_t)(b * T_SEQ + qr0[g] + ln) * DIMC + h * HDIM + quad * 8;
            aq[g][0] = *(const bf16x8*)qp;
            aq[g][1] = *(const bf16x8*)(qp + 32);
        }

        f32x4 o[2][4] = {};
        float lpart[2][4] = {};

        const int ktmax = 2 * qt + 1;
        for (int kt = 0; kt <= ktmax; ++kt) {
            const int k0 = kt * 64;
            __syncthreads();                         // Ks/Vs free to overwrite
            *(bf16x8*)&Ks[srow][scol]     = *(const bf16x8*)(kbase + (size_t)k0 * KVDIM);
            *(bf16x8*)&Ks[srow][scol + 8] = *(const bf16x8*)(kbase + (size_t)k0 * KVDIM + 8);
            *(bf16x8*)&Vs[srow][scol]     = *(const bf16x8*)(vbase + k0 + scol);
            *(bf16x8*)&Vs[srow][scol + 8] = *(const bf16x8*)(vbase + k0 + scol + 8);
            __syncthreads();                         // staging visible

            #pragma unroll
            for (int g = 0; g < 2; ++g) {
                if (kt > 2 * qt + g) continue;       // uniform: only filters g=0 at last kt
                const bool diag = (kt == 2 * qt + g);
                f32x4 s[4];
                #pragma unroll
                for (int st = 0; st < 4; ++st) {
                    f32x4 z = {};
                    s[st] = __builtin_amdgcn_mfma_f32_16x16x32_bf16(
                                aq[g][0], *(const bf16x8*)&Ks[st * 16 + ln][quad * 8], z, 0, 0, 0);
                    s[st] = __builtin_amdgcn_mfma_f32_16x16x32_bf16(
                                aq[g][1], *(const bf16x8*)&Ks[st * 16 + ln][32 + quad * 8], s[st], 0, 0, 0);
                }
                #pragma unroll
                for (int r = 0; r < 4; ++r) {
                    const int qg = qr0[g] + quad * 4 + r;
                    float e[4], rs = 0.0f;
                    #pragma unroll
                    for (int st = 0; st < 4; ++st) {
                        bool masked = diag && (k0 + st * 16 + ln > qg);
                        e[st] = masked ? 0.0f : exp2f(fmaf(s[st][r], K1, -K2));
                        rs += e[st];
                    }
                    lpart[g][r] += rs;
                    #pragma unroll
                    for (int st = 0; st < 4; ++st)
                        Ps[g][w][quad * 4 + r][st * 16 + ln] = f2bf(e[st]);
                }
            }
            // P exchange is wave-private: DS in-order per wave; fence the
            // compiler and drain lgkm before cross-lane reads.
            __asm__ __volatile__("s_waitcnt lgkmcnt(0)" ::: "memory");

            #pragma unroll
            for (int g = 0; g < 2; ++g) {
                if (kt > 2 * qt + g) continue;
                bf16x8 pa0 = *(const bf16x8*)&Ps[g][w][ln][quad * 8];
                bf16x8 pa1 = *(const bf16x8*)&Ps[g][w][ln][32 + quad * 8];
                #pragma unroll
                for (int t = 0; t < 4; ++t) {
                    o[g][t] = __builtin_amdgcn_mfma_f32_16x16x32_bf16(
                                  pa0, *(const bf16x8*)&Vs[t * 16 + ln][quad * 8], o[g][t], 0, 0, 0);
                    o[g][t] = __builtin_amdgcn_mfma_f32_16x16x32_bf16(
                                  pa1, *(const bf16x8*)&Vs[t * 16 + ln][32 + quad * 8], o[g][t], 0, 0, 0);
                }
            }
        }

        // epilogue: one cross-lane reduction of l per (g,r), normalize, store
        #pragma unroll
        for (int g = 0; g < 2; ++g) {
            #pragma unroll
            for (int r = 0; r < 4; ++r) {
                float rs = lpart[g][r];
                rs += __shfl_xor(rs, 1);
                rs += __shfl_xor(rs, 2);
                rs += __shfl_xor(rs, 4);
                rs += __shfl_xor(rs, 8);
                float inv = 1.0f / rs;
                size_t obase = (size_t)(b * T_SEQ + qr0[g] + quad * 4 + r) * DIMC + h * HDIM;
                #pragma unroll
                for (int t = 0; t < 4; ++t)
                    O[obase + t * 16 + ln] = f2bf(o[g][t][r] * inv);
            }
        }
    }
}

// ===========================================================================
extern "C" void kernel_launch(void* const* d_in, const int* in_sizes, int n_in,
                              void* d_out, int out_size, void* d_ws, size_t ws_size,
                              hipStream_t stream) {
    const float* x  = (const float*)d_in[0];
    const float* wq = (const float*)d_in[1];
    const float* wk = (const float*)d_in[2];
    const float* wv = (const float*)d_in[3];
    const float* wo = (const float*)d_in[4];
    float* out = (float*)d_out;

    char* ws = (char*)d_ws;
    constexpr size_t MB = 1024 * 1024;
    u16* Qb  = (u16*)(ws);             // 16 MB [4096][2048]
    u16* Kb  = (u16*)(ws + 16 * MB);   //  4 MB [4096][512]
    u16* Vb  = (u16*)(ws + 20 * MB);   //  4 MB [4096][512]
    u16* Vtb = (u16*)(ws + 24 * MB);   //  4 MB [2][512][2048]
    u16* AOb = (u16*)(ws + 28 * MB);   // 16 MB [4096][2048]  (aliases xb)
    u16* xb  = AOb;                    // x dead before attn writes AOb
    u16* wqb = (u16*)(ws + 44 * MB);   //  8 MB
    u16* wkb = (u16*)(ws + 52 * MB);   //  2 MB
    u16* wvb = (u16*)(ws + 54 * MB);   //  2 MB
    u16* wob = (u16*)(ws + 56 * MB);   //  8 MB
    const int M = BATCH * T_SEQ;       // 4096

    hipLaunchKernelGGL(cvt5, dim3(2048), dim3(256), 0, stream,
                       x, wq, wk, wv, wo, xb, wqb, wkb, wvb, wob);
    hipLaunchKernelGGL(qkv_gemm, dim3(24, M / 128), dim3(256), 0, stream,
                       xb, wqb, wkb, wvb, Qb, Kb, Vb);
    hipLaunchKernelGGL(transpose_v, dim3(KVDIM / 32, M / 32), dim3(256), 0, stream, Vb, Vtb);
    hipLaunchKernelGGL(attn, dim3(8, NHEAD, BATCH), dim3(256), 0, stream,
                       Qb, Kb, Vtb, AOb);
    hipLaunchKernelGGL(gemm_f32out, dim3(DIMC / 128, M / 128), dim3(256), 0, stream,
                       AOb, wob, out, DIMC, DIMC);
}

// Round 6
// 337.831 us; speedup vs baseline: 2.2680x; 1.0644x over previous
//
#include <hip/hip_runtime.h>

// Attention_6219112645023 — fp32 in / fp32 out, bf16 internal compute (MFMA).
// B=2, T=2048, DIM=2048, NH=32, NKV=8, HD=64. Causal GQA + RoPE + projections.
// Pipeline: cvt5 -> fused QKV gemm (global_load_lds) -> transpose(V) ->
// flash attn (64q tiles, balanced pairs, shuffle-free softmax) -> O gemm.
// Workspace: 64 MB. xb aliases AOb (x dead before attn writes it).
// R6: attn 64-row Q tiles (grid 1024 = 4 blocks/CU), uniform diag branch,
// truncating bf16 cvt for P. GEMMs unchanged from R5.

typedef unsigned short u16;
typedef __attribute__((ext_vector_type(8))) short bf16x8;  // 8 bf16 in 4 VGPRs
typedef __attribute__((ext_vector_type(4))) float f32x4;
typedef __attribute__((ext_vector_type(4))) unsigned short u16x4;

constexpr int T_SEQ = 2048;
constexpr int DIMC  = 2048;
constexpr int NHEAD = 32;
constexpr int HDIM  = 64;
constexpr int KVDIM = 512;   // NKV * HDIM
constexpr int BATCH = 2;

__device__ __forceinline__ u16 f2bf(float f) {
    union { float f; unsigned int i; } v; v.f = f;
    unsigned int r = v.i + 0x7FFFu + ((v.i >> 16) & 1u);   // RNE
    return (u16)(r >> 16);
}
__device__ __forceinline__ u16 f2bf_trunc(float f) {       // 1-op cvt for P in [0,1]
    union { float f; unsigned int i; } v; v.f = f;
    return (u16)(v.i >> 16);
}

typedef __attribute__((address_space(1))) unsigned int as1_uint;
typedef __attribute__((address_space(3))) unsigned int as3_uint;
__device__ __forceinline__ void glds16(const u16* g, u16* l) {
    // async global->LDS, 16B/lane; LDS dest = wave-uniform base + lane*16
    __builtin_amdgcn_global_load_lds((as1_uint*)(u16*)g, (as3_uint*)l, 16, 0, 0);
}

// ===========================================================================
// Fused fp32->bf16 convert of all 5 inputs (one launch).
// ===========================================================================
__global__ __launch_bounds__(256) void cvt5(const float* __restrict__ x,
                                            const float* __restrict__ wq,
                                            const float* __restrict__ wk,
                                            const float* __restrict__ wv,
                                            const float* __restrict__ wo,
                                            u16* __restrict__ xb,  u16* __restrict__ wqb,
                                            u16* __restrict__ wkb, u16* __restrict__ wvb,
                                            u16* __restrict__ wob) {
    constexpr int E0 = BATCH * T_SEQ * DIMC;          // 8388608
    constexpr int E1 = E0 + DIMC * DIMC;              // +4194304
    constexpr int E2 = E1 + KVDIM * DIMC;             // +1048576
    constexpr int E3 = E2 + KVDIM * DIMC;             // +1048576
    constexpr int E4 = E3 + DIMC * DIMC;              // 18874368 total
    for (int i = (blockIdx.x * 256 + threadIdx.x) * 4; i < E4; i += gridDim.x * 1024) {
        const float* s; u16* d; int off;
        if (i < E0)      { s = x;  d = xb;  off = 0;  }
        else if (i < E1) { s = wq; d = wqb; off = E0; }
        else if (i < E2) { s = wk; d = wkb; off = E1; }
        else if (i < E3) { s = wv; d = wvb; off = E2; }
        else             { s = wo; d = wob; off = E3; }
        f32x4 v = *(const f32x4*)(s + (i - off));
        u16x4 o;
        #pragma unroll
        for (int e = 0; e < 4; ++e) o[e] = f2bf(v[e]);
        *(u16x4*)(d + (i - off)) = o;
    }
}

// ===========================================================================
// m97-style GEMM core: C = A[M][K] . W[N][K]^T, bf16 in, global_load_lds
// staging into unpadded LDS, 128x128 tile, BK=32, 4 waves x 4x4 mfma tiles.
// rope (runtime, block-uniform): fused rotary on 64-col head spans.
// ===========================================================================
template <bool OUTF32>
__device__ __forceinline__ void gemm_core(const u16* __restrict__ A,
                                          const u16* __restrict__ W,
                                          void* __restrict__ Cv,
                                          int rowBase, int colBase,
                                          int N, int K, bool rope) {
    __shared__ __align__(16) u16 As[128 * 32];   // unpadded: glds lane order
    __shared__ __align__(16) u16 Bs[128 * 32];

    const int tid  = threadIdx.x;
    const int lane = tid & 63;
    const int w    = tid >> 6;
    const int quad = lane >> 4;
    const int ln   = lane & 15;
    const int wm = (w >> 1) * 64;
    const int wn = (w & 1) * 64;

    f32x4 acc[4][4] = {};

    // staging: chunk c = 16 rows; lane i -> row c*16 + (i>>2), col (i&3)*8
    const int srow = lane >> 2;
    const int scol = (lane & 3) * 8;
    const u16* aC0 = A + (size_t)(rowBase + w * 16 + srow) * K + scol;
    const u16* aC1 = A + (size_t)(rowBase + (w + 4) * 16 + srow) * K + scol;
    const u16* bC0 = W + (size_t)(colBase + w * 16 + srow) * K + scol;
    const u16* bC1 = W + (size_t)(colBase + (w + 4) * 16 + srow) * K + scol;
    u16* asl0 = As + w * 512;
    u16* asl1 = As + (w + 4) * 512;
    u16* bsl0 = Bs + w * 512;
    u16* bsl1 = Bs + (w + 4) * 512;

    for (int kk = 0; kk < K; kk += 32) {
        __syncthreads();
        glds16(aC0 + kk, asl0);
        glds16(aC1 + kk, asl1);
        glds16(bC0 + kk, bsl0);
        glds16(bC1 + kk, bsl1);
        __syncthreads();   // vmcnt(0) drain -> staged data visible

        bf16x8 bw[4];
        #pragma unroll
        for (int j = 0; j < 4; ++j) bw[j] = *(const bf16x8*)(Bs + (wn + j * 16 + ln) * 32 + quad * 8);
        #pragma unroll
        for (int i = 0; i < 4; ++i) {
            bf16x8 af = *(const bf16x8*)(As + (wm + i * 16 + ln) * 32 + quad * 8);
            #pragma unroll
            for (int j = 0; j < 4; ++j)
                acc[i][j] = __builtin_amdgcn_mfma_f32_16x16x32_bf16(af, bw[j], acc[i][j], 0, 0, 0);
        }
    }

    if (rope) {
        // head-local d = (colBase+wn+j*16+ln) % 64 = j*16+ln
        #pragma unroll
        for (int i = 0; i < 4; ++i) {
            #pragma unroll
            for (int j = 0; j < 2; ++j) {
                int d = j * 16 + ln;
                float invf = exp2f(-(float)d * (13.287712379549449f / 32.0f));
                #pragma unroll
                for (int r = 0; r < 4; ++r) {
                    int mrow = rowBase + wm + i * 16 + quad * 4 + r;
                    int t = mrow & (T_SEQ - 1);
                    float fr = (float)t * invf;
                    float sn, cs;
                    sincosf(fr, &sn, &cs);
                    float a0 = acc[i][j][r], a2 = acc[i][j + 2][r];
                    acc[i][j][r]     = a0 * cs - a2 * sn;
                    acc[i][j + 2][r] = a2 * cs + a0 * sn;
                }
            }
        }
    }

    #pragma unroll
    for (int i = 0; i < 4; ++i) {
        int mrow = rowBase + wm + i * 16 + quad * 4;
        #pragma unroll
        for (int j = 0; j < 4; ++j) {
            int n = colBase + wn + j * 16 + ln;
            #pragma unroll
            for (int r = 0; r < 4; ++r) {
                if constexpr (OUTF32)
                    ((float*)Cv)[(size_t)(mrow + r) * N + n] = acc[i][j][r];
                else
                    ((u16*)Cv)[(size_t)(mrow + r) * N + n] = f2bf(acc[i][j][r]);
            }
        }
    }
}

// Fused QKV: grid.x 0..23 -> Q cols (16 blks) | K cols (4) | V cols (4)
__global__ __launch_bounds__(256, 4) void qkv_gemm(const u16* __restrict__ xb,
                                                   const u16* __restrict__ wqb,
                                                   const u16* __restrict__ wkb,
                                                   const u16* __restrict__ wvb,
                                                   u16* __restrict__ Qb,
                                                   u16* __restrict__ Kb,
                                                   u16* __restrict__ Vb) {
    const int nb = blockIdx.x;
    const int rowBase = blockIdx.y * 128;
    const u16* W; u16* C; int colBase, N; bool rope;
    if (nb < 16)      { W = wqb; C = Qb; colBase = nb * 128;        N = DIMC;  rope = true; }
    else if (nb < 20) { W = wkb; C = Kb; colBase = (nb - 16) * 128; N = KVDIM; rope = true; }
    else              { W = wvb; C = Vb; colBase = (nb - 20) * 128; N = KVDIM; rope = false; }
    gemm_core<false>(xb, W, C, rowBase, colBase, N, DIMC, rope);
}

__global__ __launch_bounds__(256, 4) void gemm_f32out(const u16* __restrict__ A,
                                                      const u16* __restrict__ W,
                                                      float* __restrict__ C,
                                                      int N, int K) {
    gemm_core<true>(A, W, C, blockIdx.y * 128, blockIdx.x * 128, N, K, false);
}

// ===========================================================================
// V [B*T][KVDIM] -> Vt [B][KVDIM][T]
// ===========================================================================
__global__ __launch_bounds__(256) void transpose_v(const u16* __restrict__ V,
                                                   u16* __restrict__ Vt) {
    __shared__ __align__(16) u16 tile[32][33];
    const int x = threadIdx.x & 31;
    const int y = threadIdx.x >> 5;
    const int tok0 = blockIdx.y * 32;
    const int c0   = blockIdx.x * 32;
    #pragma unroll
    for (int yy = 0; yy < 32; yy += 8)
        tile[y + yy][x] = V[(size_t)(tok0 + y + yy) * KVDIM + c0 + x];
    __syncthreads();
    const int b  = tok0 >> 11;
    const int t0 = tok0 & (T_SEQ - 1);
    #pragma unroll
    for (int yy = 0; yy < 32; yy += 8)
        Vt[(size_t)(b * KVDIM + c0 + y + yy) * T_SEQ + t0 + x] = tile[x][y + yy];
}

// ===========================================================================
// Flash attention. grid = (16, NH, B), block = 256 (4 waves).
// 64-row Q tiles; block processes qt = blockIdx.x and 31-blockIdx.x
// sequentially -> 33 key-tiles per block, perfectly uniform load.
// Each wave owns 16 q-rows. 64-key tiles staged to LDS.
// Softmax: fixed shift M0=8, per-lane partial l, one epilogue reduction.
// Diagonal masking hoisted to a block-uniform branch (bulk path unmasked).
// P exchange is wave-private LDS: s_waitcnt lgkmcnt(0), no barrier.
// ===========================================================================
__global__ __launch_bounds__(256) void attn(const u16* __restrict__ Q,
                                            const u16* __restrict__ Kx,
                                            const u16* __restrict__ Vt,
                                            u16* __restrict__ O) {
    __shared__ __align__(16) u16 Ks[64][72];       // [key][dim]
    __shared__ __align__(16) u16 Vs[64][72];       // [dim][key]
    __shared__ __align__(16) u16 Ps[4][16][72];    // [wave][q][key]

    const int tid  = threadIdx.x;
    const int lane = tid & 63;
    const int w    = tid >> 6;
    const int quad = lane >> 4;
    const int ln   = lane & 15;
    const int h    = blockIdx.y;
    const int b    = blockIdx.z;
    const int kvh  = h >> 2;

    // staging: row = tid>>2 (0..63), two bf16x8 at cols (tid&3)*16 and +8
    const int srow = tid >> 2;
    const int scol = (tid & 3) * 16;
    const u16* kbase = Kx + (size_t)(b * T_SEQ + srow) * KVDIM + kvh * HDIM + scol;
    const u16* vbase = Vt + (size_t)(b * KVDIM + kvh * HDIM + srow) * T_SEQ;

    const float K1 = 0.125f * 1.4426950408889634f;   // scale * log2(e)
    const float K2 = 8.0f * 1.4426950408889634f;     // M0 * log2(e)

    #pragma unroll
    for (int phase = 0; phase < 2; ++phase) {
        const int qt = phase ? (31 - (int)blockIdx.x) : (int)blockIdx.x;
        const int qr0 = qt * 64 + w * 16;

        const u16* qp = Q + (size_t)(b * T_SEQ + qr0 + ln) * DIMC + h * HDIM + quad * 8;
        const bf16x8 aq0 = *(const bf16x8*)qp;
        const bf16x8 aq1 = *(const bf16x8*)(qp + 32);

        f32x4 o[4] = {};
        float lpart[4] = {};

        for (int kt = 0; kt <= qt; ++kt) {
            const int k0 = kt * 64;
            __syncthreads();                         // Ks/Vs free to overwrite
            *(bf16x8*)&Ks[srow][scol]     = *(const bf16x8*)(kbase + (size_t)k0 * KVDIM);
            *(bf16x8*)&Ks[srow][scol + 8] = *(const bf16x8*)(kbase + (size_t)k0 * KVDIM + 8);
            *(bf16x8*)&Vs[srow][scol]     = *(const bf16x8*)(vbase + k0 + scol);
            *(bf16x8*)&Vs[srow][scol + 8] = *(const bf16x8*)(vbase + k0 + scol + 8);
            __syncthreads();                         // staging visible

            f32x4 s[4];
            #pragma unroll
            for (int st = 0; st < 4; ++st) {
                f32x4 z = {};
                s[st] = __builtin_amdgcn_mfma_f32_16x16x32_bf16(
                            aq0, *(const bf16x8*)&Ks[st * 16 + ln][quad * 8], z, 0, 0, 0);
                s[st] = __builtin_amdgcn_mfma_f32_16x16x32_bf16(
                            aq1, *(const bf16x8*)&Ks[st * 16 + ln][32 + quad * 8], s[st], 0, 0, 0);
            }

            if (kt != qt) {
                // bulk path: fully unmasked
                #pragma unroll
                for (int r = 0; r < 4; ++r) {
                    float e[4], rs = 0.0f;
                    #pragma unroll
                    for (int st = 0; st < 4; ++st) {
                        e[st] = exp2f(fmaf(s[st][r], K1, -K2));
                        rs += e[st];
                    }
                    lpart[r] += rs;
                    #pragma unroll
                    for (int st = 0; st < 4; ++st)
                        Ps[w][quad * 4 + r][st * 16 + ln] = f2bf_trunc(e[st]);
                }
            } else {
                // diagonal tile: mask keys beyond the query row
                #pragma unroll
                for (int r = 0; r < 4; ++r) {
                    const int thr = w * 16 + quad * 4 + r;   // qg - k0
                    float e[4], rs = 0.0f;
                    #pragma unroll
                    for (int st = 0; st < 4; ++st) {
                        bool masked = (st * 16 + ln > thr);
                        e[st] = masked ? 0.0f : exp2f(fmaf(s[st][r], K1, -K2));
                        rs += e[st];
                    }
                    lpart[r] += rs;
                    #pragma unroll
                    for (int st = 0; st < 4; ++st)
                        Ps[w][quad * 4 + r][st * 16 + ln] = f2bf_trunc(e[st]);
                }
            }
            // P exchange is wave-private: DS in-order per wave; fence the
            // compiler and drain lgkm before cross-lane reads.
            __asm__ __volatile__("s_waitcnt lgkmcnt(0)" ::: "memory");

            bf16x8 pa0 = *(const bf16x8*)&Ps[w][ln][quad * 8];
            bf16x8 pa1 = *(const bf16x8*)&Ps[w][ln][32 + quad * 8];
            #pragma unroll
            for (int t = 0; t < 4; ++t) {
                o[t] = __builtin_amdgcn_mfma_f32_16x16x32_bf16(
                           pa0, *(const bf16x8*)&Vs[t * 16 + ln][quad * 8], o[t], 0, 0, 0);
                o[t] = __builtin_amdgcn_mfma_f32_16x16x32_bf16(
                           pa1, *(const bf16x8*)&Vs[t * 16 + ln][32 + quad * 8], o[t], 0, 0, 0);
            }
        }

        // epilogue: one cross-lane reduction of l per r, normalize, store
        #pragma unroll
        for (int r = 0; r < 4; ++r) {
            float rs = lpart[r];
            rs += __shfl_xor(rs, 1);
            rs += __shfl_xor(rs, 2);
            rs += __shfl_xor(rs, 4);
            rs += __shfl_xor(rs, 8);
            float inv = 1.0f / rs;
            size_t obase = (size_t)(b * T_SEQ + qr0 + quad * 4 + r) * DIMC + h * HDIM;
            #pragma unroll
            for (int t = 0; t < 4; ++t)
                O[obase + t * 16 + ln] = f2bf(o[t][r] * inv);
        }
    }
}

// ===========================================================================
extern "C" void kernel_launch(void* const* d_in, const int* in_sizes, int n_in,
                              void* d_out, int out_size, void* d_ws, size_t ws_size,
                              hipStream_t stream) {
    const float* x  = (const float*)d_in[0];
    const float* wq = (const float*)d_in[1];
    const float* wk = (const float*)d_in[2];
    const float* wv = (const float*)d_in[3];
    const float* wo = (const float*)d_in[4];
    float* out = (float*)d_out;

    char* ws = (char*)d_ws;
    constexpr size_t MB = 1024 * 1024;
    u16* Qb  = (u16*)(ws);             // 16 MB [4096][2048]
    u16* Kb  = (u16*)(ws + 16 * MB);   //  4 MB [4096][512]
    u16* Vb  = (u16*)(ws + 20 * MB);   //  4 MB [4096][512]
    u16* Vtb = (u16*)(ws + 24 * MB);   //  4 MB [2][512][2048]
    u16* AOb = (u16*)(ws + 28 * MB);   // 16 MB [4096][2048]  (aliases xb)
    u16* xb  = AOb;                    // x dead before attn writes AOb
    u16* wqb = (u16*)(ws + 44 * MB);   //  8 MB
    u16* wkb = (u16*)(ws + 52 * MB);   //  2 MB
    u16* wvb = (u16*)(ws + 54 * MB);   //  2 MB
    u16* wob = (u16*)(ws + 56 * MB);   //  8 MB
    const int M = BATCH * T_SEQ;       // 4096

    hipLaunchKernelGGL(cvt5, dim3(2048), dim3(256), 0, stream,
                       x, wq, wk, wv, wo, xb, wqb, wkb, wvb, wob);
    hipLaunchKernelGGL(qkv_gemm, dim3(24, M / 128), dim3(256), 0, stream,
                       xb, wqb, wkb, wvb, Qb, Kb, Vb);
    hipLaunchKernelGGL(transpose_v, dim3(KVDIM / 32, M / 32), dim3(256), 0, stream, Vb, Vtb);
    hipLaunchKernelGGL(attn, dim3(16, NHEAD, BATCH), dim3(256), 0, stream,
                       Qb, Kb, Vtb, AOb);
    hipLaunchKernelGGL(gemm_f32out, dim3(DIMC / 128, M / 128), dim3(256), 0, stream,
                       AOb, wob, out, DIMC, DIMC);
}

// Round 7
// 320.412 us; speedup vs baseline: 2.3913x; 1.0544x over previous
//
#include <hip/hip_runtime.h>

// Attention_6219112645023 — fp32 in / fp32 out, bf16 internal compute (MFMA).
// B=2, T=2048, DIM=2048, NH=32, NKV=8, HD=64. Causal GQA + RoPE + projections.
// Pipeline: cvt5 -> fused QKV gemm -> transpose(V) -> flash attn -> O gemm.
// R7: BK=64 (two 32-col LDS panels, barriers halved), hw-sin/cos RoPE,
// O-projection as 128x64-tile gemm_out64 (1024 blocks = 4/CU).

typedef unsigned short u16;
typedef __attribute__((ext_vector_type(8))) short bf16x8;  // 8 bf16 in 4 VGPRs
typedef __attribute__((ext_vector_type(4))) float f32x4;
typedef __attribute__((ext_vector_type(4))) unsigned short u16x4;

constexpr int T_SEQ = 2048;
constexpr int DIMC  = 2048;
constexpr int NHEAD = 32;
constexpr int HDIM  = 64;
constexpr int KVDIM = 512;   // NKV * HDIM
constexpr int BATCH = 2;

__device__ __forceinline__ u16 f2bf(float f) {
    union { float f; unsigned int i; } v; v.f = f;
    unsigned int r = v.i + 0x7FFFu + ((v.i >> 16) & 1u);   // RNE
    return (u16)(r >> 16);
}
__device__ __forceinline__ u16 f2bf_trunc(float f) {       // 1-op cvt for P in [0,1]
    union { float f; unsigned int i; } v; v.f = f;
    return (u16)(v.i >> 16);
}

typedef __attribute__((address_space(1))) unsigned int as1_uint;
typedef __attribute__((address_space(3))) unsigned int as3_uint;
__device__ __forceinline__ void glds16(const u16* g, u16* l) {
    // async global->LDS, 16B/lane; LDS dest = wave-uniform base + lane*16
    __builtin_amdgcn_global_load_lds((as1_uint*)(u16*)g, (as3_uint*)l, 16, 0, 0);
}

// ===========================================================================
// Fused fp32->bf16 convert of all 5 inputs (one launch).
// ===========================================================================
__global__ __launch_bounds__(256) void cvt5(const float* __restrict__ x,
                                            const float* __restrict__ wq,
                                            const float* __restrict__ wk,
                                            const float* __restrict__ wv,
                                            const float* __restrict__ wo,
                                            u16* __restrict__ xb,  u16* __restrict__ wqb,
                                            u16* __restrict__ wkb, u16* __restrict__ wvb,
                                            u16* __restrict__ wob) {
    constexpr int E0 = BATCH * T_SEQ * DIMC;          // 8388608
    constexpr int E1 = E0 + DIMC * DIMC;              // +4194304
    constexpr int E2 = E1 + KVDIM * DIMC;             // +1048576
    constexpr int E3 = E2 + KVDIM * DIMC;             // +1048576
    constexpr int E4 = E3 + DIMC * DIMC;              // 18874368 total
    for (int i = (blockIdx.x * 256 + threadIdx.x) * 4; i < E4; i += gridDim.x * 1024) {
        const float* s; u16* d; int off;
        if (i < E0)      { s = x;  d = xb;  off = 0;  }
        else if (i < E1) { s = wq; d = wqb; off = E0; }
        else if (i < E2) { s = wk; d = wkb; off = E1; }
        else if (i < E3) { s = wv; d = wvb; off = E2; }
        else             { s = wo; d = wob; off = E3; }
        f32x4 v = *(const f32x4*)(s + (i - off));
        u16x4 o;
        #pragma unroll
        for (int e = 0; e < 4; ++e) o[e] = f2bf(v[e]);
        *(u16x4*)(d + (i - off)) = o;
    }
}

// ===========================================================================
// GEMM core: C = A[M][K] . W[N][K]^T, bf16 in, global_load_lds staging,
// 128x128 tile, BK=64 as two 32-col LDS panels (row stride stays 32 elems ->
// same bank/chunk behavior as BK=32, half the barriers).
// rope: fused rotary, hardware v_sin/v_cos in revolutions (fract-reduced).
// ===========================================================================
template <bool OUTF32>
__device__ __forceinline__ void gemm_core(const u16* __restrict__ A,
                                          const u16* __restrict__ W,
                                          void* __restrict__ Cv,
                                          int rowBase, int colBase,
                                          int N, int K, bool rope) {
    __shared__ __align__(16) u16 As[2 * 128 * 32];   // panel h at h*4096 elems
    __shared__ __align__(16) u16 Bs[2 * 128 * 32];

    const int tid  = threadIdx.x;
    const int lane = tid & 63;
    const int w    = tid >> 6;
    const int quad = lane >> 4;
    const int ln   = lane & 15;
    const int wm = (w >> 1) * 64;
    const int wn = (w & 1) * 64;

    f32x4 acc[4][4] = {};

    // staging: chunk c = 16 rows x 32 cols; lane i -> row c*16+(i>>2), col (i&3)*8
    const int srow = lane >> 2;
    const int scol = (lane & 3) * 8;
    const u16* aC0 = A + (size_t)(rowBase + w * 16 + srow) * K + scol;
    const u16* aC1 = A + (size_t)(rowBase + (w + 4) * 16 + srow) * K + scol;
    const u16* bC0 = W + (size_t)(colBase + w * 16 + srow) * K + scol;
    const u16* bC1 = W + (size_t)(colBase + (w + 4) * 16 + srow) * K + scol;
    u16* asl0 = As + w * 512;
    u16* asl1 = As + (w + 4) * 512;
    u16* bsl0 = Bs + w * 512;
    u16* bsl1 = Bs + (w + 4) * 512;

    for (int kk = 0; kk < K; kk += 64) {
        __syncthreads();
        glds16(aC0 + kk, asl0);
        glds16(aC1 + kk, asl1);
        glds16(bC0 + kk, bsl0);
        glds16(bC1 + kk, bsl1);
        glds16(aC0 + kk + 32, asl0 + 4096);
        glds16(aC1 + kk + 32, asl1 + 4096);
        glds16(bC0 + kk + 32, bsl0 + 4096);
        glds16(bC1 + kk + 32, bsl1 + 4096);
        __syncthreads();   // vmcnt(0) drain -> both panels visible

        #pragma unroll
        for (int hp = 0; hp < 2; ++hp) {
            const u16* Ap = As + hp * 4096;
            const u16* Bp = Bs + hp * 4096;
            bf16x8 bw[4];
            #pragma unroll
            for (int j = 0; j < 4; ++j)
                bw[j] = *(const bf16x8*)(Bp + (wn + j * 16 + ln) * 32 + quad * 8);
            #pragma unroll
            for (int i = 0; i < 4; ++i) {
                bf16x8 af = *(const bf16x8*)(Ap + (wm + i * 16 + ln) * 32 + quad * 8);
                #pragma unroll
                for (int j = 0; j < 4; ++j)
                    acc[i][j] = __builtin_amdgcn_mfma_f32_16x16x32_bf16(af, bw[j], acc[i][j], 0, 0, 0);
            }
        }
    }

    if (rope) {
        // head-local d = j*16+ln; pairs (d, d+32) -> (acc[i][j], acc[i][j+2]).
        // angle = t * 10000^(-d/32); hw sin/cos take revolutions, fract-reduce.
        #pragma unroll
        for (int j = 0; j < 2; ++j) {
            const int d = j * 16 + ln;
            const float invrev = exp2f(-(float)d * (13.287712379549449f / 32.0f))
                                 * 0.15915494309189535f;   // /2pi
            #pragma unroll
            for (int i = 0; i < 4; ++i) {
                #pragma unroll
                for (int r = 0; r < 4; ++r) {
                    const int t = (rowBase + wm + i * 16 + quad * 4 + r) & (T_SEQ - 1);
                    float rev = (float)t * invrev;
                    float fr = rev - floorf(rev);
                    float sn = __builtin_amdgcn_sinf(fr);
                    float cs = __builtin_amdgcn_cosf(fr);
                    float a0 = acc[i][j][r], a2 = acc[i][j + 2][r];
                    acc[i][j][r]     = a0 * cs - a2 * sn;
                    acc[i][j + 2][r] = a2 * cs + a0 * sn;
                }
            }
        }
    }

    #pragma unroll
    for (int i = 0; i < 4; ++i) {
        int mrow = rowBase + wm + i * 16 + quad * 4;
        #pragma unroll
        for (int j = 0; j < 4; ++j) {
            int n = colBase + wn + j * 16 + ln;
            #pragma unroll
            for (int r = 0; r < 4; ++r) {
                if constexpr (OUTF32)
                    ((float*)Cv)[(size_t)(mrow + r) * N + n] = acc[i][j][r];
                else
                    ((u16*)Cv)[(size_t)(mrow + r) * N + n] = f2bf(acc[i][j][r]);
            }
        }
    }
}

// Fused QKV: grid.x 0..23 -> Q cols (16 blks) | K cols (4) | V cols (4)
__global__ __launch_bounds__(256, 4) void qkv_gemm(const u16* __restrict__ xb,
                                                   const u16* __restrict__ wqb,
                                                   const u16* __restrict__ wkb,
                                                   const u16* __restrict__ wvb,
                                                   u16* __restrict__ Qb,
                                                   u16* __restrict__ Kb,
                                                   u16* __restrict__ Vb) {
    const int nb = blockIdx.x;
    const int rowBase = blockIdx.y * 128;
    const u16* W; u16* C; int colBase, N; bool rope;
    if (nb < 16)      { W = wqb; C = Qb; colBase = nb * 128;        N = DIMC;  rope = true; }
    else if (nb < 20) { W = wkb; C = Kb; colBase = (nb - 16) * 128; N = KVDIM; rope = true; }
    else              { W = wvb; C = Vb; colBase = (nb - 20) * 128; N = KVDIM; rope = false; }
    gemm_core<false>(xb, W, C, rowBase, colBase, N, DIMC, rope);
}

// ===========================================================================
// O-projection GEMM: 128x64 tiles -> grid (32,32) = 1024 blocks = 4/CU.
// 4 waves, each 32 rows x 64 cols (acc 2x4). BK=64 two-panel staging.
// ===========================================================================
__global__ __launch_bounds__(256, 4) void gemm_out64(const u16* __restrict__ A,
                                                     const u16* __restrict__ W,
                                                     float* __restrict__ C) {
    __shared__ __align__(16) u16 As[2 * 128 * 32];   // 16 KB
    __shared__ __align__(16) u16 Bs[2 * 64 * 32];    //  8 KB

    const int tid  = threadIdx.x;
    const int lane = tid & 63;
    const int w    = tid >> 6;
    const int quad = lane >> 4;
    const int ln   = lane & 15;
    const int rowBase = blockIdx.y * 128;
    const int colBase = blockIdx.x * 64;
    const int wm = w * 32;
    constexpr int K = DIMC, N = DIMC;

    f32x4 acc[2][4] = {};

    const int srow = lane >> 2;
    const int scol = (lane & 3) * 8;
    const u16* aC0 = A + (size_t)(rowBase + w * 16 + srow) * K + scol;
    const u16* aC1 = A + (size_t)(rowBase + (w + 4) * 16 + srow) * K + scol;
    const u16* bC  = W + (size_t)(colBase + w * 16 + srow) * K + scol;
    u16* asl0 = As + w * 512;
    u16* asl1 = As + (w + 4) * 512;
    u16* bsl  = Bs + w * 512;

    for (int kk = 0; kk < K; kk += 64) {
        __syncthreads();
        glds16(aC0 + kk, asl0);
        glds16(aC1 + kk, asl1);
        glds16(bC  + kk, bsl);
        glds16(aC0 + kk + 32, asl0 + 4096);
        glds16(aC1 + kk + 32, asl1 + 4096);
        glds16(bC  + kk + 32, bsl + 2048);
        __syncthreads();

        #pragma unroll
        for (int hp = 0; hp < 2; ++hp) {
            const u16* Ap = As + hp * 4096;
            const u16* Bp = Bs + hp * 2048;
            bf16x8 bw[4];
            #pragma unroll
            for (int j = 0; j < 4; ++j)
                bw[j] = *(const bf16x8*)(Bp + (j * 16 + ln) * 32 + quad * 8);
            #pragma unroll
            for (int i = 0; i < 2; ++i) {
                bf16x8 af = *(const bf16x8*)(Ap + (wm + i * 16 + ln) * 32 + quad * 8);
                #pragma unroll
                for (int j = 0; j < 4; ++j)
                    acc[i][j] = __builtin_amdgcn_mfma_f32_16x16x32_bf16(af, bw[j], acc[i][j], 0, 0, 0);
            }
        }
    }

    #pragma unroll
    for (int i = 0; i < 2; ++i) {
        int mrow = rowBase + wm + i * 16 + quad * 4;
        #pragma unroll
        for (int j = 0; j < 4; ++j) {
            int n = colBase + j * 16 + ln;
            #pragma unroll
            for (int r = 0; r < 4; ++r)
                C[(size_t)(mrow + r) * N + n] = acc[i][j][r];
        }
    }
}

// ===========================================================================
// V [B*T][KVDIM] -> Vt [B][KVDIM][T]
// ===========================================================================
__global__ __launch_bounds__(256) void transpose_v(const u16* __restrict__ V,
                                                   u16* __restrict__ Vt) {
    __shared__ __align__(16) u16 tile[32][33];
    const int x = threadIdx.x & 31;
    const int y = threadIdx.x >> 5;
    const int tok0 = blockIdx.y * 32;
    const int c0   = blockIdx.x * 32;
    #pragma unroll
    for (int yy = 0; yy < 32; yy += 8)
        tile[y + yy][x] = V[(size_t)(tok0 + y + yy) * KVDIM + c0 + x];
    __syncthreads();
    const int b  = tok0 >> 11;
    const int t0 = tok0 & (T_SEQ - 1);
    #pragma unroll
    for (int yy = 0; yy < 32; yy += 8)
        Vt[(size_t)(b * KVDIM + c0 + y + yy) * T_SEQ + t0 + x] = tile[x][y + yy];
}

// ===========================================================================
// Flash attention. grid = (16, NH, B), block = 256 (4 waves).
// 64-row Q tiles; block processes qt = blockIdx.x and 31-blockIdx.x
// sequentially -> 33 key-tiles per block, perfectly uniform load.
// Softmax: fixed shift M0=8, per-lane partial l, one epilogue reduction.
// Diagonal masking hoisted to a block-uniform branch (bulk path unmasked).
// P exchange is wave-private LDS: s_waitcnt lgkmcnt(0), no barrier.
// ===========================================================================
__global__ __launch_bounds__(256) void attn(const u16* __restrict__ Q,
                                            const u16* __restrict__ Kx,
                                            const u16* __restrict__ Vt,
                                            u16* __restrict__ O) {
    __shared__ __align__(16) u16 Ks[64][72];       // [key][dim]
    __shared__ __align__(16) u16 Vs[64][72];       // [dim][key]
    __shared__ __align__(16) u16 Ps[4][16][72];    // [wave][q][key]

    const int tid  = threadIdx.x;
    const int lane = tid & 63;
    const int w    = tid >> 6;
    const int quad = lane >> 4;
    const int ln   = lane & 15;
    const int h    = blockIdx.y;
    const int b    = blockIdx.z;
    const int kvh  = h >> 2;

    const int srow = tid >> 2;
    const int scol = (tid & 3) * 16;
    const u16* kbase = Kx + (size_t)(b * T_SEQ + srow) * KVDIM + kvh * HDIM + scol;
    const u16* vbase = Vt + (size_t)(b * KVDIM + kvh * HDIM + srow) * T_SEQ;

    const float K1 = 0.125f * 1.4426950408889634f;   // scale * log2(e)
    const float K2 = 8.0f * 1.4426950408889634f;     // M0 * log2(e)

    #pragma unroll
    for (int phase = 0; phase < 2; ++phase) {
        const int qt = phase ? (31 - (int)blockIdx.x) : (int)blockIdx.x;
        const int qr0 = qt * 64 + w * 16;

        const u16* qp = Q + (size_t)(b * T_SEQ + qr0 + ln) * DIMC + h * HDIM + quad * 8;
        const bf16x8 aq0 = *(const bf16x8*)qp;
        const bf16x8 aq1 = *(const bf16x8*)(qp + 32);

        f32x4 o[4] = {};
        float lpart[4] = {};

        for (int kt = 0; kt <= qt; ++kt) {
            const int k0 = kt * 64;
            __syncthreads();
            *(bf16x8*)&Ks[srow][scol]     = *(const bf16x8*)(kbase + (size_t)k0 * KVDIM);
            *(bf16x8*)&Ks[srow][scol + 8] = *(const bf16x8*)(kbase + (size_t)k0 * KVDIM + 8);
            *(bf16x8*)&Vs[srow][scol]     = *(const bf16x8*)(vbase + k0 + scol);
            *(bf16x8*)&Vs[srow][scol + 8] = *(const bf16x8*)(vbase + k0 + scol + 8);
            __syncthreads();

            f32x4 s[4];
            #pragma unroll
            for (int st = 0; st < 4; ++st) {
                f32x4 z = {};
                s[st] = __builtin_amdgcn_mfma_f32_16x16x32_bf16(
                            aq0, *(const bf16x8*)&Ks[st * 16 + ln][quad * 8], z, 0, 0, 0);
                s[st] = __builtin_amdgcn_mfma_f32_16x16x32_bf16(
                            aq1, *(const bf16x8*)&Ks[st * 16 + ln][32 + quad * 8], s[st], 0, 0, 0);
            }

            if (kt != qt) {
                #pragma unroll
                for (int r = 0; r < 4; ++r) {
                    float e[4], rs = 0.0f;
                    #pragma unroll
                    for (int st = 0; st < 4; ++st) {
                        e[st] = exp2f(fmaf(s[st][r], K1, -K2));
                        rs += e[st];
                    }
                    lpart[r] += rs;
                    #pragma unroll
                    for (int st = 0; st < 4; ++st)
                        Ps[w][quad * 4 + r][st * 16 + ln] = f2bf_trunc(e[st]);
                }
            } else {
                #pragma unroll
                for (int r = 0; r < 4; ++r) {
                    const int thr = w * 16 + quad * 4 + r;   // qg - k0
                    float e[4], rs = 0.0f;
                    #pragma unroll
                    for (int st = 0; st < 4; ++st) {
                        bool masked = (st * 16 + ln > thr);
                        e[st] = masked ? 0.0f : exp2f(fmaf(s[st][r], K1, -K2));
                        rs += e[st];
                    }
                    lpart[r] += rs;
                    #pragma unroll
                    for (int st = 0; st < 4; ++st)
                        Ps[w][quad * 4 + r][st * 16 + ln] = f2bf_trunc(e[st]);
                }
            }
            __asm__ __volatile__("s_waitcnt lgkmcnt(0)" ::: "memory");

            bf16x8 pa0 = *(const bf16x8*)&Ps[w][ln][quad * 8];
            bf16x8 pa1 = *(const bf16x8*)&Ps[w][ln][32 + quad * 8];
            #pragma unroll
            for (int t = 0; t < 4; ++t) {
                o[t] = __builtin_amdgcn_mfma_f32_16x16x32_bf16(
                           pa0, *(const bf16x8*)&Vs[t * 16 + ln][quad * 8], o[t], 0, 0, 0);
                o[t] = __builtin_amdgcn_mfma_f32_16x16x32_bf16(
                           pa1, *(const bf16x8*)&Vs[t * 16 + ln][32 + quad * 8], o[t], 0, 0, 0);
            }
        }

        #pragma unroll
        for (int r = 0; r < 4; ++r) {
            float rs = lpart[r];
            rs += __shfl_xor(rs, 1);
            rs += __shfl_xor(rs, 2);
            rs += __shfl_xor(rs, 4);
            rs += __shfl_xor(rs, 8);
            float inv = 1.0f / rs;
            size_t obase = (size_t)(b * T_SEQ + qr0 + quad * 4 + r) * DIMC + h * HDIM;
            #pragma unroll
            for (int t = 0; t < 4; ++t)
                O[obase + t * 16 + ln] = f2bf(o[t][r] * inv);
        }
    }
}

// ===========================================================================
extern "C" void kernel_launch(void* const* d_in, const int* in_sizes, int n_in,
                              void* d_out, int out_size, void* d_ws, size_t ws_size,
                              hipStream_t stream) {
    const float* x  = (const float*)d_in[0];
    const float* wq = (const float*)d_in[1];
    const float* wk = (const float*)d_in[2];
    const float* wv = (const float*)d_in[3];
    const float* wo = (const float*)d_in[4];
    float* out = (float*)d_out;

    char* ws = (char*)d_ws;
    constexpr size_t MB = 1024 * 1024;
    u16* Qb  = (u16*)(ws);             // 16 MB [4096][2048]
    u16* Kb  = (u16*)(ws + 16 * MB);   //  4 MB [4096][512]
    u16* Vb  = (u16*)(ws + 20 * MB);   //  4 MB [4096][512]
    u16* Vtb = (u16*)(ws + 24 * MB);   //  4 MB [2][512][2048]
    u16* AOb = (u16*)(ws + 28 * MB);   // 16 MB [4096][2048]  (aliases xb)
    u16* xb  = AOb;                    // x dead before attn writes AOb
    u16* wqb = (u16*)(ws + 44 * MB);   //  8 MB
    u16* wkb = (u16*)(ws + 52 * MB);   //  2 MB
    u16* wvb = (u16*)(ws + 54 * MB);   //  2 MB
    u16* wob = (u16*)(ws + 56 * MB);   //  8 MB
    const int M = BATCH * T_SEQ;       // 4096

    hipLaunchKernelGGL(cvt5, dim3(2048), dim3(256), 0, stream,
                       x, wq, wk, wv, wo, xb, wqb, wkb, wvb, wob);
    hipLaunchKernelGGL(qkv_gemm, dim3(24, M / 128), dim3(256), 0, stream,
                       xb, wqb, wkb, wvb, Qb, Kb, Vb);
    hipLaunchKernelGGL(transpose_v, dim3(KVDIM / 32, M / 32), dim3(256), 0, stream, Vb, Vtb);
    hipLaunchKernelGGL(attn, dim3(16, NHEAD, BATCH), dim3(256), 0, stream,
                       Qb, Kb, Vtb, AOb);
    hipLaunchKernelGGL(gemm_out64, dim3(DIMC / 64, M / 128), dim3(256), 0, stream,
                       AOb, wob, out);
}